// Round 1
// baseline (562.538 us; speedup 1.0000x reference)
//
#include <hip/hip_runtime.h>
#include <hip/hip_bf16.h>

// EditModel: bidi prior LSTM (H=256) + modern LSTM (H=512) + factored
// logit heads. Key identity: ctx@W^T = prior@W^T (+) modern@W^T, so no
// [P,M,B,2H] tensor is ever built. One-hot inputs => Wih projection is a
// column gather done on the fly in the recurrent kernel.

#define PLEN 32
#define MLEN 32
#define BATCH 128
#define HP 256
#define HMOD 512
#define DIN 54
#define OUTV 53

typedef __bf16 bf16x8 __attribute__((ext_vector_type(8)));
typedef float f32x4 __attribute__((ext_vector_type(4)));

// ---- workspace layout (bytes), all 256B-aligned ----
#define WS_CNT      0          // 3*64 u32 barrier counters (memset each call)
#define WS_SRCIDX   1024       // 32*128 int
#define WS_WHH_PF   17408      // 1024*256 bf16
#define WS_WHH_PB   541696
#define WS_WHH_M    1065984    // 2048*512 bf16
#define WS_WSUB     3163136    // 64*512 bf16 (rows >=53 zero-padded)
#define WS_WINS     3228672
#define WS_HF       3294208    // 32*128*256 bf16  hidden history, fwd prior
#define WS_HB       5391360    // backward prior (step-indexed)
#define WS_HM       7488512    // 32*128*512 bf16  modern
#define WS_SPS      11682816   // 4096*64 f32: (prior@Wsub^T + b_sub)
#define WS_SPI      12731392
#define WS_SMS      13779968   // 4096*64 f32: modern@Wsub^T
#define WS_SMI      14828544

#define OFF_END 131072         // PLEN*MLEN*BATCH
#define OFF_SUB 262144
#define OFF_INS 389120         // 262144 + 32*31*128

__device__ __forceinline__ float sigf(float x) { return 1.0f / (1.0f + __expf(-x)); }
__device__ __forceinline__ float tanhfast(float x) {
  x = fminf(15.0f, fmaxf(-15.0f, x));
  float e = __expf(2.0f * x);
  return (e - 1.0f) / (e + 1.0f);
}

__global__ void prep_kernel(const float* __restrict__ Whh_pf, const float* __restrict__ Whh_pb,
                            const float* __restrict__ Whh_m,
                            const float* __restrict__ W_sub, const float* __restrict__ W_ins,
                            const float* __restrict__ src_oh,
                            __hip_bfloat16* __restrict__ whh_pf_b, __hip_bfloat16* __restrict__ whh_pb_b,
                            __hip_bfloat16* __restrict__ whh_m_b,
                            __hip_bfloat16* __restrict__ wsub_b, __hip_bfloat16* __restrict__ wins_b,
                            int* __restrict__ src_idx)
{
  int tid = blockIdx.x * blockDim.x + threadIdx.x;
  int stride = gridDim.x * blockDim.x;
  for (int k = tid; k < 4 * HP * HP; k += stride) {
    whh_pf_b[k] = __float2bfloat16(Whh_pf[k]);
    whh_pb_b[k] = __float2bfloat16(Whh_pb[k]);
  }
  for (int k = tid; k < 4 * HMOD * HMOD; k += stride)
    whh_m_b[k] = __float2bfloat16(Whh_m[k]);
  for (int k = tid; k < 64 * HMOD; k += stride) {
    int r = k >> 9, c = k & 511;
    wsub_b[k] = __float2bfloat16(r < OUTV ? W_sub[r * HMOD + c] : 0.0f);
    wins_b[k] = __float2bfloat16(r < OUTV ? W_ins[r * HMOD + c] : 0.0f);
  }
  for (int k = tid; k < PLEN * BATCH; k += stride) {
    const float* row = src_oh + (size_t)k * DIN;
    int idx = 0;
    for (int j = 0; j < DIN; ++j) if (row[j] > 0.5f) idx = j;
    src_idx[k] = idx;
  }
}

// Persistent recurrent kernel. 64 WGs: [0,32) modern, [32,48) prior-fwd,
// [48,64) prior-bwd. Each WG owns 16 hidden units (all 4 gates), computes
// G = h_prev @ Whh^T via MFMA, gathers Wih[:,idx]+bias, does the cell
// update with c in registers, writes h to hist[t], then a per-LSTM
// device-scope barrier so every WG sees all h[t] before step t+1.
__global__ __launch_bounds__(256, 1) void lstm_kernel(
    const float* __restrict__ Wih_pf, const float* __restrict__ b_pf,
    const float* __restrict__ Wih_pb, const float* __restrict__ b_pb,
    const float* __restrict__ Wih_m,  const float* __restrict__ b_m,
    const int* __restrict__ src_idx,  const int* __restrict__ tgt_idx,
    const __hip_bfloat16* __restrict__ whh_pf_b, const __hip_bfloat16* __restrict__ whh_pb_b,
    const __hip_bfloat16* __restrict__ whh_m_b,
    __hip_bfloat16* __restrict__ hf, __hip_bfloat16* __restrict__ hb,
    __hip_bfloat16* __restrict__ hm,
    unsigned* __restrict__ cnt)
{
  int wg = blockIdx.x;
  int wgl, nwg, H;
  const __hip_bfloat16* whh; const float* wih; const float* bias; const int* idx;
  __hip_bfloat16* hist; bool rev; unsigned* mycnt;
  if (wg < 32)      { wgl = wg;      nwg = 32; H = HMOD; whh = whh_m_b;  wih = Wih_m;  bias = b_m;  idx = tgt_idx; hist = hm; rev = false; mycnt = cnt; }
  else if (wg < 48) { wgl = wg - 32; nwg = 16; H = HP;   whh = whh_pf_b; wih = Wih_pf; bias = b_pf; idx = src_idx; hist = hf; rev = false; mycnt = cnt + 64; }
  else              { wgl = wg - 48; nwg = 16; H = HP;   whh = whh_pb_b; wih = Wih_pb; bias = b_pb; idx = src_idx; hist = hb; rev = true;  mycnt = cnt + 128; }

  const int lane = threadIdx.x & 63;
  const int wv   = threadIdx.x >> 6;
  const int l15  = lane & 15;
  const int kg   = lane >> 4;
  const int col  = wgl * 16 + l15;   // hidden unit owned by this lane's C columns
  const int bt0  = wv * 2;           // two 16-row b-tiles per wave

  float bgate[4];
  #pragma unroll
  for (int g = 0; g < 4; ++g) bgate[g] = bias[g * H + col];

  float cst[2][4];
  #pragma unroll
  for (int i = 0; i < 2; ++i)
    #pragma unroll
    for (int r = 0; r < 4; ++r) cst[i][r] = 0.f;

  for (int t = 0; t < 32; ++t) {
    f32x4 acc[2][4];
    #pragma unroll
    for (int i = 0; i < 2; ++i)
      #pragma unroll
      for (int g = 0; g < 4; ++g) acc[i][g] = (f32x4){0.f, 0.f, 0.f, 0.f};

    if (t > 0) {
      if (threadIdx.x == 0) {
        while (__hip_atomic_load(&mycnt[t - 1], __ATOMIC_RELAXED, __HIP_MEMORY_SCOPE_AGENT) != (unsigned)nwg)
          __builtin_amdgcn_s_sleep(1);
        (void)__hip_atomic_load(&mycnt[t - 1], __ATOMIC_ACQUIRE, __HIP_MEMORY_SCOPE_AGENT);
      }
      __syncthreads();
      const __hip_bfloat16* hprev = hist + (size_t)(t - 1) * BATCH * H;
      const int nk = H >> 5;
      for (int kk = 0; kk < nk; ++kk) {
        int kb = kk * 32 + kg * 8;
        bf16x8 a0 = *reinterpret_cast<const bf16x8*>(hprev + (size_t)(bt0 * 16 + l15) * H + kb);
        bf16x8 a1 = *reinterpret_cast<const bf16x8*>(hprev + (size_t)((bt0 + 1) * 16 + l15) * H + kb);
        #pragma unroll
        for (int g = 0; g < 4; ++g) {
          bf16x8 bfr = *reinterpret_cast<const bf16x8*>(whh + (size_t)(g * H + col) * H + kb);
          acc[0][g] = __builtin_amdgcn_mfma_f32_16x16x32_bf16(a0, bfr, acc[0][g], 0, 0, 0);
          acc[1][g] = __builtin_amdgcn_mfma_f32_16x16x32_bf16(a1, bfr, acc[1][g], 0, 0, 0);
        }
      }
    }

    int tin = rev ? (31 - t) : t;
    __hip_bfloat16* hout = hist + (size_t)t * BATCH * H;
    #pragma unroll
    for (int bt = 0; bt < 2; ++bt) {
      #pragma unroll
      for (int r = 0; r < 4; ++r) {
        int b = (bt0 + bt) * 16 + kg * 4 + r;   // C layout: row=(lane>>4)*4+reg
        int ii = idx[tin * BATCH + b];
        float gi = acc[bt][0][r] + wih[(size_t)(0 * H + col) * DIN + ii] + bgate[0];
        float gf = acc[bt][1][r] + wih[(size_t)(1 * H + col) * DIN + ii] + bgate[1];
        float gg = acc[bt][2][r] + wih[(size_t)(2 * H + col) * DIN + ii] + bgate[2];
        float go = acc[bt][3][r] + wih[(size_t)(3 * H + col) * DIN + ii] + bgate[3];
        float c = sigf(gf) * cst[bt][r] + sigf(gi) * tanhfast(gg);
        cst[bt][r] = c;
        hout[(size_t)b * H + col] = __float2bfloat16(sigf(go) * tanhfast(c));
      }
    }
    __syncthreads();
    if (threadIdx.x == 0)
      __hip_atomic_fetch_add(&mycnt[t], 1u, __ATOMIC_RELEASE, __HIP_MEMORY_SCOPE_AGENT);
  }
}

// Head projections: SP*[p*128+b][64] = prior @ W^T (+bias), SM*[m*128+b][64].
// prior[...,k] = hf[p] (k<256) else hb[31-p] (concat + time reversal).
__global__ __launch_bounds__(256, 1) void proj_kernel(
    const __hip_bfloat16* __restrict__ hf, const __hip_bfloat16* __restrict__ hb,
    const __hip_bfloat16* __restrict__ hm,
    const __hip_bfloat16* __restrict__ wsub_b, const __hip_bfloat16* __restrict__ wins_b,
    const float* __restrict__ b_sub, const float* __restrict__ b_ins,
    float* __restrict__ SPs, float* __restrict__ SPi,
    float* __restrict__ SMs, float* __restrict__ SMi)
{
  int wg = blockIdx.x;
  bool prior = wg < 64;
  int rowbase = (wg & 63) * 64;
  const int lane = threadIdx.x & 63;
  const int wv = threadIdx.x >> 6;
  const int l15 = lane & 15;
  const int kg = lane >> 4;
  int arow = rowbase + wv * 16 + l15;

  f32x4 acc[2][4];
  #pragma unroll
  for (int i = 0; i < 2; ++i)
    #pragma unroll
    for (int ct = 0; ct < 4; ++ct) acc[i][ct] = (f32x4){0.f, 0.f, 0.f, 0.f};

  for (int kk = 0; kk < 16; ++kk) {
    int kb = kk * 32 + kg * 8;
    bf16x8 a;
    if (prior) {
      int p = arow >> 7, b = arow & 127;
      if (kb < HP) a = *reinterpret_cast<const bf16x8*>(hf + ((size_t)p * BATCH + b) * HP + kb);
      else         a = *reinterpret_cast<const bf16x8*>(hb + ((size_t)(31 - p) * BATCH + b) * HP + (kb - HP));
    } else {
      a = *reinterpret_cast<const bf16x8*>(hm + (size_t)arow * HMOD + kb);
    }
    #pragma unroll
    for (int ct = 0; ct < 4; ++ct) {
      bf16x8 bs = *reinterpret_cast<const bf16x8*>(wsub_b + (size_t)(ct * 16 + l15) * HMOD + kb);
      bf16x8 bi = *reinterpret_cast<const bf16x8*>(wins_b + (size_t)(ct * 16 + l15) * HMOD + kb);
      acc[0][ct] = __builtin_amdgcn_mfma_f32_16x16x32_bf16(a, bs, acc[0][ct], 0, 0, 0);
      acc[1][ct] = __builtin_amdgcn_mfma_f32_16x16x32_bf16(a, bi, acc[1][ct], 0, 0, 0);
    }
  }
  #pragma unroll
  for (int ct = 0; ct < 4; ++ct) {
    int colo = ct * 16 + l15;
    #pragma unroll
    for (int r = 0; r < 4; ++r) {
      int row = rowbase + wv * 16 + kg * 4 + r;
      if (prior) {
        SPs[(size_t)row * 64 + colo] = acc[0][ct][r] + (colo < OUTV ? b_sub[colo] : 0.f);
        SPi[(size_t)row * 64 + colo] = acc[1][ct][r] + (colo < OUTV ? b_ins[colo] : 0.f);
      } else {
        SMs[(size_t)row * 64 + colo] = acc[0][ct][r];
        SMi[(size_t)row * 64 + colo] = acc[1][ct][r];
      }
    }
  }
}

// Final: one WG per batch b. LDS holds SP*/SM* rows for this b; each thread
// does 4 (p,m) pairs: 53-wide logsumexp for sub and ins heads, then writes
// p_del/p_end (channel 52) and p_sub/p_ins (gather at targets_idx[m+1,b]).
__global__ __launch_bounds__(256, 1) void out_kernel(
    const float* __restrict__ SPs, const float* __restrict__ SPi,
    const float* __restrict__ SMs, const float* __restrict__ SMi,
    const int* __restrict__ tgt_idx, float* __restrict__ out)
{
  int b = blockIdx.x;
  __shared__ float sps[32][66], spi[32][66], sms[32][66], smi[32][66];
  __shared__ int tg[32];
  for (int i = threadIdx.x; i < 32 * 64; i += 256) {
    int p = i >> 6, o = i & 63;
    size_t base = ((size_t)p * BATCH + b) * 64 + o;
    sps[p][o] = SPs[base]; spi[p][o] = SPi[base];
    sms[p][o] = SMs[base]; smi[p][o] = SMi[base];
  }
  if (threadIdx.x < 32) tg[threadIdx.x] = tgt_idx[threadIdx.x * BATCH + b];
  __syncthreads();

  for (int pr = threadIdx.x; pr < PLEN * MLEN; pr += 256) {
    int p = pr >> 5, m = pr & 31;
    float mxs = -1e30f, mxi = -1e30f;
    for (int o = 0; o < OUTV; ++o) {
      mxs = fmaxf(mxs, sps[p][o] + sms[m][o]);
      mxi = fmaxf(mxi, spi[p][o] + smi[m][o]);
    }
    float ss = 0.f, si = 0.f;
    for (int o = 0; o < OUTV; ++o) {
      ss += __expf(sps[p][o] + sms[m][o] - mxs);
      si += __expf(spi[p][o] + smi[m][o] - mxi);
    }
    float lses = mxs + __logf(ss);
    float lsei = mxi + __logf(si);
    size_t pm = (size_t)(p * MLEN + m) * BATCH + b;
    out[pm] = sps[p][52] + sms[m][52] - lses;
    out[OFF_END + pm] = spi[p][52] + smi[m][52] - lsei;
    if (m < 31) {
      int tt = tg[m + 1];
      size_t pms = (size_t)(p * 31 + m) * BATCH + b;
      out[OFF_SUB + pms] = sps[p][tt] + sms[m][tt] - lses;
      out[OFF_INS + pms] = spi[p][tt] + smi[m][tt] - lsei;
    }
  }
}

extern "C" void kernel_launch(void* const* d_in, const int* in_sizes, int n_in,
                              void* d_out, int out_size, void* d_ws, size_t ws_size,
                              hipStream_t stream) {
  const float* src_oh = (const float*)d_in[0];
  const float* Wih_pf = (const float*)d_in[2];
  const float* Whh_pf = (const float*)d_in[3];
  const float* b_pf   = (const float*)d_in[4];
  const float* Wih_pb = (const float*)d_in[5];
  const float* Whh_pb = (const float*)d_in[6];
  const float* b_pb   = (const float*)d_in[7];
  const float* Wih_m  = (const float*)d_in[8];
  const float* Whh_m  = (const float*)d_in[9];
  const float* b_m    = (const float*)d_in[10];
  const float* W_sub  = (const float*)d_in[11];
  const float* b_sub  = (const float*)d_in[12];
  const float* W_ins  = (const float*)d_in[13];
  const float* b_ins  = (const float*)d_in[14];
  const int*   tgt    = (const int*)d_in[15];

  char* ws = (char*)d_ws;
  unsigned* cnt = (unsigned*)(ws + WS_CNT);
  int* src_idx = (int*)(ws + WS_SRCIDX);
  __hip_bfloat16* whh_pf_b = (__hip_bfloat16*)(ws + WS_WHH_PF);
  __hip_bfloat16* whh_pb_b = (__hip_bfloat16*)(ws + WS_WHH_PB);
  __hip_bfloat16* whh_m_b  = (__hip_bfloat16*)(ws + WS_WHH_M);
  __hip_bfloat16* wsub_b   = (__hip_bfloat16*)(ws + WS_WSUB);
  __hip_bfloat16* wins_b   = (__hip_bfloat16*)(ws + WS_WINS);
  __hip_bfloat16* hf = (__hip_bfloat16*)(ws + WS_HF);
  __hip_bfloat16* hb = (__hip_bfloat16*)(ws + WS_HB);
  __hip_bfloat16* hm = (__hip_bfloat16*)(ws + WS_HM);
  float* SPs = (float*)(ws + WS_SPS);
  float* SPi = (float*)(ws + WS_SPI);
  float* SMs = (float*)(ws + WS_SMS);
  float* SMi = (float*)(ws + WS_SMI);

  hipMemsetAsync(cnt, 0, 1024, stream);
  prep_kernel<<<256, 256, 0, stream>>>(Whh_pf, Whh_pb, Whh_m, W_sub, W_ins, src_oh,
                                       whh_pf_b, whh_pb_b, whh_m_b, wsub_b, wins_b, src_idx);
  lstm_kernel<<<64, 256, 0, stream>>>(Wih_pf, b_pf, Wih_pb, b_pb, Wih_m, b_m,
                                      src_idx, tgt, whh_pf_b, whh_pb_b, whh_m_b,
                                      hf, hb, hm, cnt);
  proj_kernel<<<128, 256, 0, stream>>>(hf, hb, hm, wsub_b, wins_b, b_sub, b_ins,
                                       SPs, SPi, SMs, SMi);
  out_kernel<<<128, 256, 0, stream>>>(SPs, SPi, SMs, SMi, tgt, (float*)d_out);
}

// Round 2
// 555.319 us; speedup vs baseline: 1.0130x; 1.0130x over previous
//
#include <hip/hip_runtime.h>
#include <hip/hip_bf16.h>

// EditModel: bidi prior LSTM (H=256) + modern LSTM (H=512) + factored
// logit heads. ctx@W^T = prior@W^T (+) modern@W^T so no [P,M,B,2H] tensor.
// LSTM sync: h is exchanged through L3 via sc0/sc1 (cache-bypass) loads and
// stores + per-WG monotonic flags (relaxed agent atomics). No acquire/release
// fences => no buffer_inv/wbl2 => Whh stays L2-resident across all steps.

#define PLEN 32
#define MLEN 32
#define BATCH 128
#define HP 256
#define HMOD 512
#define DIN 54
#define OUTV 53

typedef __bf16 bf16x8 __attribute__((ext_vector_type(8)));
typedef float f32x4 __attribute__((ext_vector_type(4)));
typedef int i32x4 __attribute__((ext_vector_type(4)));

// ---- workspace layout (bytes) ----
#define WS_CNT      0          // flag arrays: [0..31] modern, [64..79] pf, [128..143] pb
#define WS_SRCIDX   1024
#define WS_WHH_PF   17408
#define WS_WHH_PB   541696
#define WS_WHH_M    1065984
#define WS_WSUB     3163136
#define WS_WINS     3228672
#define WS_HF       3294208
#define WS_HB       5391360
#define WS_HM       7488512
#define WS_SPS      11682816
#define WS_SPI      12731392
#define WS_SMS      13779968
#define WS_SMI      14828544

#define OFF_END 131072
#define OFF_SUB 262144
#define OFF_INS 389120

__device__ __forceinline__ float sigf(float x) { return 1.0f / (1.0f + __expf(-x)); }
__device__ __forceinline__ float tanhfast(float x) {
  x = fminf(15.0f, fmaxf(-15.0f, x));
  float e = __expf(2.0f * x);
  return (e - 1.0f) / (e + 1.0f);
}

// L2/L1-bypass 16B ops: data goes to / comes from the coherent point (L3).
__device__ __forceinline__ void store_cc16(void* p, i32x4 v) {
  asm volatile("global_store_dwordx4 %0, %1, off sc0 sc1" :: "v"(p), "v"(v) : "memory");
}
__device__ __forceinline__ i32x4 load_cc16(const void* p) {
  i32x4 r;
  asm volatile("global_load_dwordx4 %0, %1, off sc0 sc1" : "=v"(r) : "v"(p) : "memory");
  return r;
}

__global__ void prep_kernel(const float* __restrict__ Whh_pf, const float* __restrict__ Whh_pb,
                            const float* __restrict__ Whh_m,
                            const float* __restrict__ W_sub, const float* __restrict__ W_ins,
                            const float* __restrict__ src_oh,
                            __hip_bfloat16* __restrict__ whh_pf_b, __hip_bfloat16* __restrict__ whh_pb_b,
                            __hip_bfloat16* __restrict__ whh_m_b,
                            __hip_bfloat16* __restrict__ wsub_b, __hip_bfloat16* __restrict__ wins_b,
                            int* __restrict__ src_idx)
{
  int tid = blockIdx.x * blockDim.x + threadIdx.x;
  int stride = gridDim.x * blockDim.x;
  for (int k = tid; k < 4 * HP * HP; k += stride) {
    whh_pf_b[k] = __float2bfloat16(Whh_pf[k]);
    whh_pb_b[k] = __float2bfloat16(Whh_pb[k]);
  }
  for (int k = tid; k < 4 * HMOD * HMOD; k += stride)
    whh_m_b[k] = __float2bfloat16(Whh_m[k]);
  for (int k = tid; k < 64 * HMOD; k += stride) {
    int r = k >> 9, c = k & 511;
    wsub_b[k] = __float2bfloat16(r < OUTV ? W_sub[r * HMOD + c] : 0.0f);
    wins_b[k] = __float2bfloat16(r < OUTV ? W_ins[r * HMOD + c] : 0.0f);
  }
  for (int k = tid; k < PLEN * BATCH; k += stride) {
    const float* row = src_oh + (size_t)k * DIN;
    int idx = 0;
    for (int j = 0; j < DIN; ++j) if (row[j] > 0.5f) idx = j;
    src_idx[k] = idx;
  }
}

// One LSTM step body, column-partitioned: WG wgl owns 16 hidden units (all
// 4 gates). A-fragments (h_prev) come via bypass loads; B (Whh) via normal
// cached loads (L2 stays warm). Epilogue bounces h through LDS to make
// coalesced 16B write-through stores, then posts flag = t+1.
template<int H, int NWG, bool REV>
__device__ __forceinline__ void lstm_body(
    const float* __restrict__ wih, const float* __restrict__ bias,
    const int* __restrict__ idx, const __hip_bfloat16* __restrict__ whh,
    __hip_bfloat16* __restrict__ hist, unsigned* flags, int wgl,
    __hip_bfloat16 (*lds_h)[24])
{
  constexpr int NK = H / 32;
  const int tid = threadIdx.x;
  const int lane = tid & 63;
  const int wv = tid >> 6;
  const int l15 = lane & 15;
  const int kg = lane >> 4;
  const int col = wgl * 16 + l15;
  const int bt0 = wv * 2;

  float bgate[4];
  #pragma unroll
  for (int g = 0; g < 4; ++g) bgate[g] = bias[g * H + col];

  float cst[2][4];
  #pragma unroll
  for (int i = 0; i < 2; ++i)
    #pragma unroll
    for (int r = 0; r < 4; ++r) cst[i][r] = 0.f;

  for (int t = 0; t < 32; ++t) {
    int tin = REV ? (31 - t) : t;

    // Input-projection gather issued BEFORE the poll: latency hides under it.
    float win[2][4][4];
    #pragma unroll
    for (int bt = 0; bt < 2; ++bt)
      #pragma unroll
      for (int r = 0; r < 4; ++r) {
        int b = (bt0 + bt) * 16 + kg * 4 + r;
        int ii = idx[tin * BATCH + b];
        #pragma unroll
        for (int g = 0; g < 4; ++g)
          win[bt][r][g] = wih[(size_t)(g * H + col) * DIN + ii];
      }

    f32x4 acc[2][4];
    #pragma unroll
    for (int i = 0; i < 2; ++i)
      #pragma unroll
      for (int g = 0; g < 4; ++g) acc[i][g] = (f32x4){0.f, 0.f, 0.f, 0.f};

    if (t > 0) {
      // Poll all producer flags (relaxed, sc1-bypass loads: no cache inv).
      unsigned want = (unsigned)t;
      for (;;) {
        unsigned v = __hip_atomic_load(&flags[lane & (NWG - 1)],
                                       __ATOMIC_RELAXED, __HIP_MEMORY_SCOPE_AGENT);
        if (__all(v >= want)) break;
        __builtin_amdgcn_s_sleep(1);
      }
      __builtin_amdgcn_sched_barrier(0);

      // Issue ALL A-fragment bypass loads, then one drain.
      const __hip_bfloat16* hprev = hist + (size_t)(t - 1) * (BATCH * H);
      i32x4 a[2][NK];
      #pragma unroll
      for (int kk = 0; kk < NK; ++kk) {
        int kb = kk * 32 + kg * 8;
        a[0][kk] = load_cc16(hprev + (size_t)(bt0 * 16 + l15) * H + kb);
        a[1][kk] = load_cc16(hprev + (size_t)((bt0 + 1) * 16 + l15) * H + kb);
      }
      asm volatile("s_waitcnt vmcnt(0)" ::: "memory");
      __builtin_amdgcn_sched_barrier(0);

      #pragma unroll
      for (int kk = 0; kk < NK; ++kk) {
        int kb = kk * 32 + kg * 8;
        bf16x8 a0 = __builtin_bit_cast(bf16x8, a[0][kk]);
        bf16x8 a1 = __builtin_bit_cast(bf16x8, a[1][kk]);
        #pragma unroll
        for (int g = 0; g < 4; ++g) {
          bf16x8 bfr = *reinterpret_cast<const bf16x8*>(whh + (size_t)(g * H + col) * H + kb);
          acc[0][g] = __builtin_amdgcn_mfma_f32_16x16x32_bf16(a0, bfr, acc[0][g], 0, 0, 0);
          acc[1][g] = __builtin_amdgcn_mfma_f32_16x16x32_bf16(a1, bfr, acc[1][g], 0, 0, 0);
        }
      }
    }

    // Cell update; h -> LDS bounce (padded rows: stride 24 bf16 = 48B).
    #pragma unroll
    for (int bt = 0; bt < 2; ++bt) {
      #pragma unroll
      for (int r = 0; r < 4; ++r) {
        int b = (bt0 + bt) * 16 + kg * 4 + r;
        float gi = acc[bt][0][r] + win[bt][r][0] + bgate[0];
        float gf = acc[bt][1][r] + win[bt][r][1] + bgate[1];
        float gg = acc[bt][2][r] + win[bt][r][2] + bgate[2];
        float go = acc[bt][3][r] + win[bt][r][3] + bgate[3];
        float c = sigf(gf) * cst[bt][r] + sigf(gi) * tanhfast(gg);
        cst[bt][r] = c;
        lds_h[b][l15] = __float2bfloat16(sigf(go) * tanhfast(c));
      }
    }
    __syncthreads();

    // Coalesced write-through: 256 threads x 16B = this WG's 128x16 h slice.
    {
      int b = tid >> 1, o = (tid & 1) * 8;
      i32x4 v = *reinterpret_cast<const i32x4*>(&lds_h[b][o]);
      __hip_bfloat16* dst = hist + (size_t)t * (BATCH * H) + (size_t)b * H + wgl * 16 + o;
      store_cc16(dst, v);
    }
    asm volatile("s_waitcnt vmcnt(0)" ::: "memory");
    __syncthreads();  // all waves' stores drained
    if (tid == 0)
      __hip_atomic_store(&flags[wgl], (unsigned)(t + 1),
                         __ATOMIC_RELAXED, __HIP_MEMORY_SCOPE_AGENT);
  }
}

__global__ __launch_bounds__(256, 1) void lstm_kernel(
    const float* __restrict__ Wih_pf, const float* __restrict__ b_pf,
    const float* __restrict__ Wih_pb, const float* __restrict__ b_pb,
    const float* __restrict__ Wih_m,  const float* __restrict__ b_m,
    const int* __restrict__ src_idx,  const int* __restrict__ tgt_idx,
    const __hip_bfloat16* __restrict__ whh_pf_b, const __hip_bfloat16* __restrict__ whh_pb_b,
    const __hip_bfloat16* __restrict__ whh_m_b,
    __hip_bfloat16* __restrict__ hf, __hip_bfloat16* __restrict__ hb,
    __hip_bfloat16* __restrict__ hm,
    unsigned* __restrict__ cnt)
{
  __shared__ __align__(16) __hip_bfloat16 lds_h[128][24];
  int wg = blockIdx.x;
  if (wg < 32)
    lstm_body<HMOD, 32, false>(Wih_m, b_m, tgt_idx, whh_m_b, hm, cnt, wg, lds_h);
  else if (wg < 48)
    lstm_body<HP, 16, false>(Wih_pf, b_pf, src_idx, whh_pf_b, hf, cnt + 64, wg - 32, lds_h);
  else
    lstm_body<HP, 16, true>(Wih_pb, b_pb, src_idx, whh_pb_b, hb, cnt + 128, wg - 48, lds_h);
}

__global__ __launch_bounds__(256, 1) void proj_kernel(
    const __hip_bfloat16* __restrict__ hf, const __hip_bfloat16* __restrict__ hb,
    const __hip_bfloat16* __restrict__ hm,
    const __hip_bfloat16* __restrict__ wsub_b, const __hip_bfloat16* __restrict__ wins_b,
    const float* __restrict__ b_sub, const float* __restrict__ b_ins,
    float* __restrict__ SPs, float* __restrict__ SPi,
    float* __restrict__ SMs, float* __restrict__ SMi)
{
  int wg = blockIdx.x;
  bool prior = wg < 64;
  int rowbase = (wg & 63) * 64;
  const int lane = threadIdx.x & 63;
  const int wv = threadIdx.x >> 6;
  const int l15 = lane & 15;
  const int kg = lane >> 4;
  int arow = rowbase + wv * 16 + l15;

  f32x4 acc[2][4];
  #pragma unroll
  for (int i = 0; i < 2; ++i)
    #pragma unroll
    for (int ct = 0; ct < 4; ++ct) acc[i][ct] = (f32x4){0.f, 0.f, 0.f, 0.f};

  for (int kk = 0; kk < 16; ++kk) {
    int kb = kk * 32 + kg * 8;
    bf16x8 a;
    if (prior) {
      int p = arow >> 7, b = arow & 127;
      if (kb < HP) a = *reinterpret_cast<const bf16x8*>(hf + ((size_t)p * BATCH + b) * HP + kb);
      else         a = *reinterpret_cast<const bf16x8*>(hb + ((size_t)(31 - p) * BATCH + b) * HP + (kb - HP));
    } else {
      a = *reinterpret_cast<const bf16x8*>(hm + (size_t)arow * HMOD + kb);
    }
    #pragma unroll
    for (int ct = 0; ct < 4; ++ct) {
      bf16x8 bs = *reinterpret_cast<const bf16x8*>(wsub_b + (size_t)(ct * 16 + l15) * HMOD + kb);
      bf16x8 bi = *reinterpret_cast<const bf16x8*>(wins_b + (size_t)(ct * 16 + l15) * HMOD + kb);
      acc[0][ct] = __builtin_amdgcn_mfma_f32_16x16x32_bf16(a, bs, acc[0][ct], 0, 0, 0);
      acc[1][ct] = __builtin_amdgcn_mfma_f32_16x16x32_bf16(a, bi, acc[1][ct], 0, 0, 0);
    }
  }
  #pragma unroll
  for (int ct = 0; ct < 4; ++ct) {
    int colo = ct * 16 + l15;
    #pragma unroll
    for (int r = 0; r < 4; ++r) {
      int row = rowbase + wv * 16 + kg * 4 + r;
      if (prior) {
        SPs[(size_t)row * 64 + colo] = acc[0][ct][r] + (colo < OUTV ? b_sub[colo] : 0.f);
        SPi[(size_t)row * 64 + colo] = acc[1][ct][r] + (colo < OUTV ? b_ins[colo] : 0.f);
      } else {
        SMs[(size_t)row * 64 + colo] = acc[0][ct][r];
        SMi[(size_t)row * 64 + colo] = acc[1][ct][r];
      }
    }
  }
}

__global__ __launch_bounds__(256, 1) void out_kernel(
    const float* __restrict__ SPs, const float* __restrict__ SPi,
    const float* __restrict__ SMs, const float* __restrict__ SMi,
    const int* __restrict__ tgt_idx, float* __restrict__ out)
{
  int b = blockIdx.x;
  __shared__ float sps[32][66], spi[32][66], sms[32][66], smi[32][66];
  __shared__ int tg[32];
  for (int i = threadIdx.x; i < 32 * 64; i += 256) {
    int p = i >> 6, o = i & 63;
    size_t base = ((size_t)p * BATCH + b) * 64 + o;
    sps[p][o] = SPs[base]; spi[p][o] = SPi[base];
    sms[p][o] = SMs[base]; smi[p][o] = SMi[base];
  }
  if (threadIdx.x < 32) tg[threadIdx.x] = tgt_idx[threadIdx.x * BATCH + b];
  __syncthreads();

  for (int pr = threadIdx.x; pr < PLEN * MLEN; pr += 256) {
    int p = pr >> 5, m = pr & 31;
    float mxs = -1e30f, mxi = -1e30f;
    for (int o = 0; o < OUTV; ++o) {
      mxs = fmaxf(mxs, sps[p][o] + sms[m][o]);
      mxi = fmaxf(mxi, spi[p][o] + smi[m][o]);
    }
    float ss = 0.f, si = 0.f;
    for (int o = 0; o < OUTV; ++o) {
      ss += __expf(sps[p][o] + sms[m][o] - mxs);
      si += __expf(spi[p][o] + smi[m][o] - mxi);
    }
    float lses = mxs + __logf(ss);
    float lsei = mxi + __logf(si);
    size_t pm = (size_t)(p * MLEN + m) * BATCH + b;
    out[pm] = sps[p][52] + sms[m][52] - lses;
    out[OFF_END + pm] = spi[p][52] + smi[m][52] - lsei;
    if (m < 31) {
      int tt = tg[m + 1];
      size_t pms = (size_t)(p * 31 + m) * BATCH + b;
      out[OFF_SUB + pms] = sps[p][tt] + sms[m][tt] - lses;
      out[OFF_INS + pms] = spi[p][tt] + smi[m][tt] - lsei;
    }
  }
}

extern "C" void kernel_launch(void* const* d_in, const int* in_sizes, int n_in,
                              void* d_out, int out_size, void* d_ws, size_t ws_size,
                              hipStream_t stream) {
  const float* src_oh = (const float*)d_in[0];
  const float* Wih_pf = (const float*)d_in[2];
  const float* Whh_pf = (const float*)d_in[3];
  const float* b_pf   = (const float*)d_in[4];
  const float* Wih_pb = (const float*)d_in[5];
  const float* Whh_pb = (const float*)d_in[6];
  const float* b_pb   = (const float*)d_in[7];
  const float* Wih_m  = (const float*)d_in[8];
  const float* Whh_m  = (const float*)d_in[9];
  const float* b_m    = (const float*)d_in[10];
  const float* W_sub  = (const float*)d_in[11];
  const float* b_sub  = (const float*)d_in[12];
  const float* W_ins  = (const float*)d_in[13];
  const float* b_ins  = (const float*)d_in[14];
  const int*   tgt    = (const int*)d_in[15];

  char* ws = (char*)d_ws;
  unsigned* cnt = (unsigned*)(ws + WS_CNT);
  int* src_idx = (int*)(ws + WS_SRCIDX);
  __hip_bfloat16* whh_pf_b = (__hip_bfloat16*)(ws + WS_WHH_PF);
  __hip_bfloat16* whh_pb_b = (__hip_bfloat16*)(ws + WS_WHH_PB);
  __hip_bfloat16* whh_m_b  = (__hip_bfloat16*)(ws + WS_WHH_M);
  __hip_bfloat16* wsub_b   = (__hip_bfloat16*)(ws + WS_WSUB);
  __hip_bfloat16* wins_b   = (__hip_bfloat16*)(ws + WS_WINS);
  __hip_bfloat16* hf = (__hip_bfloat16*)(ws + WS_HF);
  __hip_bfloat16* hb = (__hip_bfloat16*)(ws + WS_HB);
  __hip_bfloat16* hm = (__hip_bfloat16*)(ws + WS_HM);
  float* SPs = (float*)(ws + WS_SPS);
  float* SPi = (float*)(ws + WS_SPI);
  float* SMs = (float*)(ws + WS_SMS);
  float* SMi = (float*)(ws + WS_SMI);

  hipMemsetAsync(cnt, 0, 1024, stream);
  prep_kernel<<<256, 256, 0, stream>>>(Whh_pf, Whh_pb, Whh_m, W_sub, W_ins, src_oh,
                                       whh_pf_b, whh_pb_b, whh_m_b, wsub_b, wins_b, src_idx);
  lstm_kernel<<<64, 256, 0, stream>>>(Wih_pf, b_pf, Wih_pb, b_pb, Wih_m, b_m,
                                      src_idx, tgt, whh_pf_b, whh_pb_b, whh_m_b,
                                      hf, hb, hm, cnt);
  proj_kernel<<<128, 256, 0, stream>>>(hf, hb, hm, wsub_b, wins_b, b_sub, b_ins,
                                       SPs, SPi, SMs, SMi);
  out_kernel<<<128, 256, 0, stream>>>(SPs, SPi, SMs, SMi, tgt, (float*)d_out);
}

// Round 3
// 367.009 us; speedup vs baseline: 1.5328x; 1.5131x over previous
//
#include <hip/hip_runtime.h>
#include <hip/hip_bf16.h>

// EditModel: bidi prior LSTM (H=256) + modern LSTM (H=512) + factored
// logit heads. ctx@W^T = prior@W^T (+) modern@W^T so no [P,M,B,2H] tensor.
//
// LSTM phase is XCD-LOCAL: WGs read HW_REG_XCC_ID, self-organize so each
// LSTM's WGs share one XCD; h + flags exchanged through that XCD's L2 via
// sc0 (L1-bypass) ops only -- no L3 round trips, no cache fences. Whh is
// staged once into LDS in MFMA-fragment order (conflict-free ds_read_b128).

#define PLEN 32
#define MLEN 32
#define BATCH 128
#define HP 256
#define HMOD 512
#define DIN 54
#define OUTV 53
#define NWGS 256

typedef __bf16 bf16x8 __attribute__((ext_vector_type(8)));
typedef float f32x4 __attribute__((ext_vector_type(4)));
typedef int i32x4 __attribute__((ext_vector_type(4)));

// ---- workspace layout (bytes) ----
// ctl (u32): [0..7] per-XCD reg count, [8] total, [32..63] flags modern,
//            [64..79] flags pf, [96..111] flags pb   (memset 1024B each call)
#define WS_CNT      0
#define WS_SRCIDX   1024
#define WS_WHH_PF   17408
#define WS_WHH_PB   541696
#define WS_WHH_M    1065984
#define WS_WSUB     3163136
#define WS_WINS     3228672
#define WS_HF       3294208
#define WS_HB       5391360
#define WS_HM       7488512
#define WS_SPS      11682816
#define WS_SPI      12731392
#define WS_SMS      13779968
#define WS_SMI      14828544

#define OFF_END 131072
#define OFF_SUB 262144
#define OFF_INS 389120

__device__ __forceinline__ float sigf(float x) { return 1.0f / (1.0f + __expf(-x)); }
__device__ __forceinline__ float tanhfast(float x) {
  x = fminf(15.0f, fmaxf(-15.0f, x));
  float e = __expf(2.0f * x);
  return (e - 1.0f) / (e + 1.0f);
}

// Intra-XCD coherent ops: sc0 = bypass L1, hit the XCD-shared L2.
__device__ __forceinline__ i32x4 load_l2_16(const void* p) {
  i32x4 r;
  asm volatile("global_load_dwordx4 %0, %1, off sc0" : "=v"(r) : "v"(p) : "memory");
  return r;
}
__device__ __forceinline__ void store_l2_short(void* p, unsigned v) {
  asm volatile("global_store_short %0, %1, off sc0" :: "v"(p), "v"(v) : "memory");
}
__device__ __forceinline__ void store_l2_dword(void* p, unsigned v) {
  asm volatile("global_store_dword %0, %1, off sc0" :: "v"(p), "v"(v) : "memory");
}
__device__ __forceinline__ unsigned load_l2_dword(const void* p) {
  unsigned v;
  asm volatile("global_load_dword %0, %1, off sc0\n\ts_waitcnt vmcnt(0)"
               : "=v"(v) : "v"(p) : "memory");
  return v;
}

__global__ void prep_kernel(const float* __restrict__ Whh_pf, const float* __restrict__ Whh_pb,
                            const float* __restrict__ Whh_m,
                            const float* __restrict__ W_sub, const float* __restrict__ W_ins,
                            const float* __restrict__ src_oh,
                            __hip_bfloat16* __restrict__ whh_pf_b, __hip_bfloat16* __restrict__ whh_pb_b,
                            __hip_bfloat16* __restrict__ whh_m_b,
                            __hip_bfloat16* __restrict__ wsub_b, __hip_bfloat16* __restrict__ wins_b,
                            int* __restrict__ src_idx)
{
  int tid = blockIdx.x * blockDim.x + threadIdx.x;
  int stride = gridDim.x * blockDim.x;
  for (int k = tid; k < 4 * HP * HP; k += stride) {
    whh_pf_b[k] = __float2bfloat16(Whh_pf[k]);
    whh_pb_b[k] = __float2bfloat16(Whh_pb[k]);
  }
  for (int k = tid; k < 4 * HMOD * HMOD; k += stride)
    whh_m_b[k] = __float2bfloat16(Whh_m[k]);
  for (int k = tid; k < 64 * HMOD; k += stride) {
    int r = k >> 9, c = k & 511;
    wsub_b[k] = __float2bfloat16(r < OUTV ? W_sub[r * HMOD + c] : 0.0f);
    wins_b[k] = __float2bfloat16(r < OUTV ? W_ins[r * HMOD + c] : 0.0f);
  }
  for (int k = tid; k < PLEN * BATCH; k += stride) {
    const float* row = src_oh + (size_t)k * DIN;
    int idx = 0;
    for (int j = 0; j < DIN; ++j) if (row[j] > 0.5f) idx = j;
    src_idx[k] = idx;
  }
}

// One LSTM, column-partitioned: WG wgl owns 16 hidden units (all 4 gates).
// All participating WGs are on ONE XCD: h + flags move through its L2 (sc0).
// Whh slice lives in LDS in fragment order: block (kk,g) at 1KB offset,
// lane l's 16B at l*16  => ds_read_b128 at the bank-bandwidth floor.
template<int H, int NWG, bool REV>
__device__ __forceinline__ void lstm_body(
    const float* __restrict__ wih, const float* __restrict__ bias,
    const int* __restrict__ idx, const __hip_bfloat16* __restrict__ whh,
    __hip_bfloat16* __restrict__ hist, unsigned* flags, int wgl, char* lds)
{
  constexpr int NK = H / 32;       // k-blocks of 32
  constexpr int CPR = H / 8;       // 16B chunks per weight row
  const int tid = threadIdx.x;
  const int lane = tid & 63;
  const int wv = tid >> 6;
  const int l15 = lane & 15;
  const int kg = lane >> 4;
  const int col = wgl * 16 + l15;
  const int bt0 = wv * 2;

  // ---- stage Whh slice into LDS, fragment order ----
  for (int ch = tid; ch < 64 * CPR; ch += 256) {
    int r = ch / CPR, cb = ch % CPR;      // r = g*16+c, cb = kk*4+kg2
    int g = r >> 4, c = r & 15;
    int kk = cb >> 2, kg2 = cb & 3;
    i32x4 v = *reinterpret_cast<const i32x4*>(
        reinterpret_cast<const char*>(whh) + ((size_t)(g * H + wgl * 16 + c) * H) * 2 + cb * 16);
    *reinterpret_cast<i32x4*>(lds + (((kk * 4 + g) * 64) + kg2 * 16 + c) * 16) = v;
  }

  float bgate[4];
  #pragma unroll
  for (int g = 0; g < 4; ++g) bgate[g] = bias[g * H + col];

  float cst[2][4];
  #pragma unroll
  for (int i = 0; i < 2; ++i)
    #pragma unroll
    for (int r = 0; r < 4; ++r) cst[i][r] = 0.f;

  __syncthreads();   // LDS B ready

  for (int t = 0; t < 32; ++t) {
    int tin = REV ? (31 - t) : t;

    // Input-projection gather issued BEFORE the poll (latency hides there).
    float win[2][4][4];
    #pragma unroll
    for (int bt = 0; bt < 2; ++bt)
      #pragma unroll
      for (int r = 0; r < 4; ++r) {
        int b = (bt0 + bt) * 16 + kg * 4 + r;
        int ii = idx[tin * BATCH + b];
        #pragma unroll
        for (int g = 0; g < 4; ++g)
          win[bt][r][g] = wih[(size_t)(g * H + col) * DIN + ii];
      }

    f32x4 acc[2][4];
    #pragma unroll
    for (int i = 0; i < 2; ++i)
      #pragma unroll
      for (int g = 0; g < 4; ++g) acc[i][g] = (f32x4){0.f, 0.f, 0.f, 0.f};

    if (t > 0) {
      // Poll producer flags through the XCD-local L2.
      const unsigned want = (unsigned)t;
      for (;;) {
        unsigned v = load_l2_dword(flags + (lane & (NWG - 1)));
        if (__all(v >= want)) break;
        __builtin_amdgcn_s_sleep(1);
      }
      __builtin_amdgcn_sched_barrier(0);

      // Issue ALL A-fragment loads (L2-local), one drain, then MFMA.
      const __hip_bfloat16* hprev = hist + (size_t)(t - 1) * (BATCH * H);
      i32x4 a[2][NK];
      #pragma unroll
      for (int kk = 0; kk < NK; ++kk) {
        int kb = kk * 32 + kg * 8;
        a[0][kk] = load_l2_16(hprev + (size_t)(bt0 * 16 + l15) * H + kb);
        a[1][kk] = load_l2_16(hprev + (size_t)((bt0 + 1) * 16 + l15) * H + kb);
      }
      asm volatile("s_waitcnt vmcnt(0)" ::: "memory");
      __builtin_amdgcn_sched_barrier(0);

      #pragma unroll
      for (int kk = 0; kk < NK; ++kk) {
        bf16x8 a0 = __builtin_bit_cast(bf16x8, a[0][kk]);
        bf16x8 a1 = __builtin_bit_cast(bf16x8, a[1][kk]);
        #pragma unroll
        for (int g = 0; g < 4; ++g) {
          bf16x8 bfr = *reinterpret_cast<const bf16x8*>(lds + (((kk * 4 + g) * 64) + lane) * 16);
          acc[0][g] = __builtin_amdgcn_mfma_f32_16x16x32_bf16(a0, bfr, acc[0][g], 0, 0, 0);
          acc[1][g] = __builtin_amdgcn_mfma_f32_16x16x32_bf16(a1, bfr, acc[1][g], 0, 0, 0);
        }
      }
    }

    // Cell update; h stores are tiny (4KB/WG) -> direct scattered sc0 stores.
    __hip_bfloat16* hout = hist + (size_t)t * (BATCH * H);
    #pragma unroll
    for (int bt = 0; bt < 2; ++bt) {
      #pragma unroll
      for (int r = 0; r < 4; ++r) {
        int b = (bt0 + bt) * 16 + kg * 4 + r;
        float gi = acc[bt][0][r] + win[bt][r][0] + bgate[0];
        float gf = acc[bt][1][r] + win[bt][r][1] + bgate[1];
        float gg = acc[bt][2][r] + win[bt][r][2] + bgate[2];
        float go = acc[bt][3][r] + win[bt][r][3] + bgate[3];
        float c = sigf(gf) * cst[bt][r] + sigf(gi) * tanhfast(gg);
        cst[bt][r] = c;
        __hip_bfloat16 hv = __float2bfloat16(sigf(go) * tanhfast(c));
        unsigned hb = (unsigned)__builtin_bit_cast(unsigned short, hv);
        store_l2_short(hout + (size_t)b * H + col, hb);
      }
    }
    asm volatile("s_waitcnt vmcnt(0)" ::: "memory");
    __syncthreads();   // all waves' h stores are in L2
    if (tid == 0)
      store_l2_dword(flags + wgl, (unsigned)(t + 1));
  }
}

__global__ __launch_bounds__(256, 1) void lstm_kernel(
    const float* __restrict__ Wih_pf, const float* __restrict__ b_pf,
    const float* __restrict__ Wih_pb, const float* __restrict__ b_pb,
    const float* __restrict__ Wih_m,  const float* __restrict__ b_m,
    const int* __restrict__ src_idx,  const int* __restrict__ tgt_idx,
    const __hip_bfloat16* __restrict__ whh_pf_b, const __hip_bfloat16* __restrict__ whh_pb_b,
    const __hip_bfloat16* __restrict__ whh_m_b,
    __hip_bfloat16* __restrict__ hf, __hip_bfloat16* __restrict__ hb,
    __hip_bfloat16* __restrict__ hm,
    unsigned* __restrict__ ctl)
{
  __shared__ __align__(16) char lds[65536];

  // ---- registration: which XCD am I on, what's my rank there ----
  unsigned xcc;
  asm volatile("s_getreg_b32 %0, hwreg(HW_REG_XCC_ID)" : "=s"(xcc));
  xcc &= 7;
  unsigned* srank = reinterpret_cast<unsigned*>(lds);
  if (threadIdx.x == 0) {
    unsigned r = __hip_atomic_fetch_add(&ctl[xcc], 1u, __ATOMIC_RELAXED, __HIP_MEMORY_SCOPE_AGENT);
    asm volatile("s_waitcnt vmcnt(0)" ::: "memory");   // cnt-add visible before total-add
    __hip_atomic_fetch_add(&ctl[8], 1u, __ATOMIC_RELAXED, __HIP_MEMORY_SCOPE_AGENT);
    while (__hip_atomic_load(&ctl[8], __ATOMIC_RELAXED, __HIP_MEMORY_SCOPE_AGENT) < (unsigned)NWGS)
      __builtin_amdgcn_s_sleep(8);
    srank[0] = r;
  }
  __syncthreads();
  unsigned rank = srank[0];
  __syncthreads();   // everyone has read srank before LDS is reused for B

  unsigned counts[8];
  #pragma unroll
  for (int x = 0; x < 8; ++x)
    counts[x] = __hip_atomic_load(&ctl[x], __ATOMIC_RELAXED, __HIP_MEMORY_SCOPE_AGENT);

  // Greedy deterministic assignment (identical in every WG): modern(32) on
  // the fullest XCD, then pf(16), pb(16). Pigeonhole with 256 WGs / 8 XCDs
  // guarantees feasibility; multiple groups may share an XCD.
  int role = -1, wgl = 0;
  {
    unsigned rem[8];
    #pragma unroll
    for (int x = 0; x < 8; ++x) rem[x] = counts[x];
    const unsigned needs[3] = {32u, 16u, 16u};
    for (int g = 0; g < 3; ++g) {
      int best = 0;
      for (int x = 1; x < 8; ++x) if (rem[x] > rem[best]) best = x;
      unsigned base = counts[best] - rem[best];
      if ((int)xcc == best && rank >= base && rank < base + needs[g]) {
        role = g; wgl = (int)(rank - base);
      }
      rem[best] -= (rem[best] >= needs[g]) ? needs[g] : rem[best];
    }
  }
  if (role < 0) return;

  if (role == 0)
    lstm_body<HMOD, 32, false>(Wih_m, b_m, tgt_idx, whh_m_b, hm, ctl + 32, wgl, lds);
  else if (role == 1)
    lstm_body<HP, 16, false>(Wih_pf, b_pf, src_idx, whh_pf_b, hf, ctl + 64, wgl, lds);
  else
    lstm_body<HP, 16, true>(Wih_pb, b_pb, src_idx, whh_pb_b, hb, ctl + 96, wgl, lds);
}

__global__ __launch_bounds__(256, 1) void proj_kernel(
    const __hip_bfloat16* __restrict__ hf, const __hip_bfloat16* __restrict__ hb,
    const __hip_bfloat16* __restrict__ hm,
    const __hip_bfloat16* __restrict__ wsub_b, const __hip_bfloat16* __restrict__ wins_b,
    const float* __restrict__ b_sub, const float* __restrict__ b_ins,
    float* __restrict__ SPs, float* __restrict__ SPi,
    float* __restrict__ SMs, float* __restrict__ SMi)
{
  int wg = blockIdx.x;
  bool prior = wg < 64;
  int rowbase = (wg & 63) * 64;
  const int lane = threadIdx.x & 63;
  const int wv = threadIdx.x >> 6;
  const int l15 = lane & 15;
  const int kg = lane >> 4;
  int arow = rowbase + wv * 16 + l15;

  f32x4 acc[2][4];
  #pragma unroll
  for (int i = 0; i < 2; ++i)
    #pragma unroll
    for (int ct = 0; ct < 4; ++ct) acc[i][ct] = (f32x4){0.f, 0.f, 0.f, 0.f};

  for (int kk = 0; kk < 16; ++kk) {
    int kb = kk * 32 + kg * 8;
    bf16x8 a;
    if (prior) {
      int p = arow >> 7, b = arow & 127;
      if (kb < HP) a = *reinterpret_cast<const bf16x8*>(hf + ((size_t)p * BATCH + b) * HP + kb);
      else         a = *reinterpret_cast<const bf16x8*>(hb + ((size_t)(31 - p) * BATCH + b) * HP + (kb - HP));
    } else {
      a = *reinterpret_cast<const bf16x8*>(hm + (size_t)arow * HMOD + kb);
    }
    #pragma unroll
    for (int ct = 0; ct < 4; ++ct) {
      bf16x8 bs = *reinterpret_cast<const bf16x8*>(wsub_b + (size_t)(ct * 16 + l15) * HMOD + kb);
      bf16x8 bi = *reinterpret_cast<const bf16x8*>(wins_b + (size_t)(ct * 16 + l15) * HMOD + kb);
      acc[0][ct] = __builtin_amdgcn_mfma_f32_16x16x32_bf16(a, bs, acc[0][ct], 0, 0, 0);
      acc[1][ct] = __builtin_amdgcn_mfma_f32_16x16x32_bf16(a, bi, acc[1][ct], 0, 0, 0);
    }
  }
  #pragma unroll
  for (int ct = 0; ct < 4; ++ct) {
    int colo = ct * 16 + l15;
    #pragma unroll
    for (int r = 0; r < 4; ++r) {
      int row = rowbase + wv * 16 + kg * 4 + r;
      if (prior) {
        SPs[(size_t)row * 64 + colo] = acc[0][ct][r] + (colo < OUTV ? b_sub[colo] : 0.f);
        SPi[(size_t)row * 64 + colo] = acc[1][ct][r] + (colo < OUTV ? b_ins[colo] : 0.f);
      } else {
        SMs[(size_t)row * 64 + colo] = acc[0][ct][r];
        SMi[(size_t)row * 64 + colo] = acc[1][ct][r];
      }
    }
  }
}

__global__ __launch_bounds__(256, 1) void out_kernel(
    const float* __restrict__ SPs, const float* __restrict__ SPi,
    const float* __restrict__ SMs, const float* __restrict__ SMi,
    const int* __restrict__ tgt_idx, float* __restrict__ out)
{
  int b = blockIdx.x;
  __shared__ float sps[32][66], spi[32][66], sms[32][66], smi[32][66];
  __shared__ int tg[32];
  for (int i = threadIdx.x; i < 32 * 64; i += 256) {
    int p = i >> 6, o = i & 63;
    size_t base = ((size_t)p * BATCH + b) * 64 + o;
    sps[p][o] = SPs[base]; spi[p][o] = SPi[base];
    sms[p][o] = SMs[base]; smi[p][o] = SMi[base];
  }
  if (threadIdx.x < 32) tg[threadIdx.x] = tgt_idx[threadIdx.x * BATCH + b];
  __syncthreads();

  for (int pr = threadIdx.x; pr < PLEN * MLEN; pr += 256) {
    int p = pr >> 5, m = pr & 31;
    float mxs = -1e30f, mxi = -1e30f;
    for (int o = 0; o < OUTV; ++o) {
      mxs = fmaxf(mxs, sps[p][o] + sms[m][o]);
      mxi = fmaxf(mxi, spi[p][o] + smi[m][o]);
    }
    float ss = 0.f, si = 0.f;
    for (int o = 0; o < OUTV; ++o) {
      ss += __expf(sps[p][o] + sms[m][o] - mxs);
      si += __expf(spi[p][o] + smi[m][o] - mxi);
    }
    float lses = mxs + __logf(ss);
    float lsei = mxi + __logf(si);
    size_t pm = (size_t)(p * MLEN + m) * BATCH + b;
    out[pm] = sps[p][52] + sms[m][52] - lses;
    out[OFF_END + pm] = spi[p][52] + smi[m][52] - lsei;
    if (m < 31) {
      int tt = tg[m + 1];
      size_t pms = (size_t)(p * 31 + m) * BATCH + b;
      out[OFF_SUB + pms] = sps[p][tt] + sms[m][tt] - lses;
      out[OFF_INS + pms] = spi[p][tt] + smi[m][tt] - lsei;
    }
  }
}

extern "C" void kernel_launch(void* const* d_in, const int* in_sizes, int n_in,
                              void* d_out, int out_size, void* d_ws, size_t ws_size,
                              hipStream_t stream) {
  const float* src_oh = (const float*)d_in[0];
  const float* Wih_pf = (const float*)d_in[2];
  const float* Whh_pf = (const float*)d_in[3];
  const float* b_pf   = (const float*)d_in[4];
  const float* Wih_pb = (const float*)d_in[5];
  const float* Whh_pb = (const float*)d_in[6];
  const float* b_pb   = (const float*)d_in[7];
  const float* Wih_m  = (const float*)d_in[8];
  const float* Whh_m  = (const float*)d_in[9];
  const float* b_m    = (const float*)d_in[10];
  const float* W_sub  = (const float*)d_in[11];
  const float* b_sub  = (const float*)d_in[12];
  const float* W_ins  = (const float*)d_in[13];
  const float* b_ins  = (const float*)d_in[14];
  const int*   tgt    = (const int*)d_in[15];

  char* ws = (char*)d_ws;
  unsigned* ctl = (unsigned*)(ws + WS_CNT);
  int* src_idx = (int*)(ws + WS_SRCIDX);
  __hip_bfloat16* whh_pf_b = (__hip_bfloat16*)(ws + WS_WHH_PF);
  __hip_bfloat16* whh_pb_b = (__hip_bfloat16*)(ws + WS_WHH_PB);
  __hip_bfloat16* whh_m_b  = (__hip_bfloat16*)(ws + WS_WHH_M);
  __hip_bfloat16* wsub_b   = (__hip_bfloat16*)(ws + WS_WSUB);
  __hip_bfloat16* wins_b   = (__hip_bfloat16*)(ws + WS_WINS);
  __hip_bfloat16* hf = (__hip_bfloat16*)(ws + WS_HF);
  __hip_bfloat16* hb = (__hip_bfloat16*)(ws + WS_HB);
  __hip_bfloat16* hm = (__hip_bfloat16*)(ws + WS_HM);
  float* SPs = (float*)(ws + WS_SPS);
  float* SPi = (float*)(ws + WS_SPI);
  float* SMs = (float*)(ws + WS_SMS);
  float* SMi = (float*)(ws + WS_SMI);

  hipMemsetAsync(ctl, 0, 1024, stream);
  prep_kernel<<<256, 256, 0, stream>>>(Whh_pf, Whh_pb, Whh_m, W_sub, W_ins, src_oh,
                                       whh_pf_b, whh_pb_b, whh_m_b, wsub_b, wins_b, src_idx);
  lstm_kernel<<<NWGS, 256, 0, stream>>>(Wih_pf, b_pf, Wih_pb, b_pb, Wih_m, b_m,
                                        src_idx, tgt, whh_pf_b, whh_pb_b, whh_m_b,
                                        hf, hb, hm, ctl);
  proj_kernel<<<128, 256, 0, stream>>>(hf, hb, hm, wsub_b, wins_b, b_sub, b_ins,
                                       SPs, SPi, SMs, SMi);
  out_kernel<<<128, 256, 0, stream>>>(SPs, SPi, SMs, SMi, tgt, (float*)d_out);
}

// Round 4
// 357.042 us; speedup vs baseline: 1.5756x; 1.0279x over previous
//
#include <hip/hip_runtime.h>
#include <hip/hip_bf16.h>

// EditModel: bidi prior LSTM (H=256) + modern LSTM (H=512) + factored
// logit heads. ctx@W^T = prior@W^T (+) modern@W^T so no [P,M,B,2H] tensor.
//
// LSTM phase is XCD-LOCAL (WGs self-organize via HW_REG_XCC_ID; h + flags
// through the XCD's L2 with sc0 ops). This round: Whh lives in VGPRs
// (loaded once, loop-invariant) -- no ds_read in the recurrent loop; the
// per-CU LDS unit was the serialized bottleneck (~6k cyc/step).

#define PLEN 32
#define MLEN 32
#define BATCH 128
#define HP 256
#define HMOD 512
#define DIN 54
#define OUTV 53
#define NWGS 256

typedef __bf16 bf16x8 __attribute__((ext_vector_type(8)));
typedef float f32x4 __attribute__((ext_vector_type(4)));
typedef int i32x4 __attribute__((ext_vector_type(4)));

// ---- workspace layout (bytes) ----
// ctl (u32): [0..7] per-XCD reg count, [8] total, [32..63] flags modern,
//            [64..79] flags pf, [96..111] flags pb   (memset 1024B each call)
#define WS_CNT      0
#define WS_SRCIDX   1024
#define WS_WHH_PF   17408
#define WS_WHH_PB   541696
#define WS_WHH_M    1065984
#define WS_WSUB     3163136
#define WS_WINS     3228672
#define WS_HF       3294208
#define WS_HB       5391360
#define WS_HM       7488512
#define WS_SPS      11682816
#define WS_SPI      12731392
#define WS_SMS      13779968
#define WS_SMI      14828544

#define OFF_END 131072
#define OFF_SUB 262144
#define OFF_INS 389120

__device__ __forceinline__ float sigf(float x) { return 1.0f / (1.0f + __expf(-x)); }
__device__ __forceinline__ float tanhfast(float x) {
  x = fminf(15.0f, fmaxf(-15.0f, x));
  float e = __expf(2.0f * x);
  return (e - 1.0f) / (e + 1.0f);
}

// Intra-XCD coherent ops: sc0 = bypass L1, hit the XCD-shared L2.
__device__ __forceinline__ i32x4 load_l2_16(const void* p) {
  i32x4 r;
  asm volatile("global_load_dwordx4 %0, %1, off sc0" : "=v"(r) : "v"(p) : "memory");
  return r;
}
__device__ __forceinline__ void store_l2_16(void* p, i32x4 v) {
  asm volatile("global_store_dwordx4 %0, %1, off sc0" :: "v"(p), "v"(v) : "memory");
}
__device__ __forceinline__ void store_l2_dword(void* p, unsigned v) {
  asm volatile("global_store_dword %0, %1, off sc0" :: "v"(p), "v"(v) : "memory");
}
__device__ __forceinline__ unsigned load_l2_dword(const void* p) {
  unsigned v;
  asm volatile("global_load_dword %0, %1, off sc0\n\ts_waitcnt vmcnt(0)"
               : "=v"(v) : "v"(p) : "memory");
  return v;
}

__global__ void prep_kernel(const float* __restrict__ Whh_pf, const float* __restrict__ Whh_pb,
                            const float* __restrict__ Whh_m,
                            const float* __restrict__ W_sub, const float* __restrict__ W_ins,
                            const float* __restrict__ src_oh,
                            __hip_bfloat16* __restrict__ whh_pf_b, __hip_bfloat16* __restrict__ whh_pb_b,
                            __hip_bfloat16* __restrict__ whh_m_b,
                            __hip_bfloat16* __restrict__ wsub_b, __hip_bfloat16* __restrict__ wins_b,
                            int* __restrict__ src_idx)
{
  int tid = blockIdx.x * blockDim.x + threadIdx.x;
  int stride = gridDim.x * blockDim.x;
  for (int k = tid; k < 4 * HP * HP; k += stride) {
    whh_pf_b[k] = __float2bfloat16(Whh_pf[k]);
    whh_pb_b[k] = __float2bfloat16(Whh_pb[k]);
  }
  for (int k = tid; k < 4 * HMOD * HMOD; k += stride)
    whh_m_b[k] = __float2bfloat16(Whh_m[k]);
  for (int k = tid; k < 64 * HMOD; k += stride) {
    int r = k >> 9, c = k & 511;
    wsub_b[k] = __float2bfloat16(r < OUTV ? W_sub[r * HMOD + c] : 0.0f);
    wins_b[k] = __float2bfloat16(r < OUTV ? W_ins[r * HMOD + c] : 0.0f);
  }
  for (int k = tid; k < PLEN * BATCH; k += stride) {
    const float* row = src_oh + (size_t)k * DIN;
    int idx = 0;
    for (int j = 0; j < DIN; ++j) if (row[j] > 0.5f) idx = j;
    src_idx[k] = idx;
  }
}

// One LSTM, column-partitioned: WG wgl owns 16 hidden units (all 4 gates).
// All participating WGs share ONE XCD; h + flags move through its L2 (sc0).
// B (Whh slice) is loaded ONCE into VGPRs in MFMA fragment layout; the
// t-loop contains no LDS reads. A is burst-loaded and consumed in halves.
template<int H, int NWG, bool REV>
__device__ __forceinline__ void lstm_body(
    const float* __restrict__ wih, const float* __restrict__ bias,
    const int* __restrict__ idx, const __hip_bfloat16* __restrict__ whh,
    __hip_bfloat16* __restrict__ hist, unsigned* flags, int wgl,
    __hip_bfloat16 (*lds_h)[24])
{
  constexpr int NK = H / 32;       // k-blocks of 32
  const int tid = threadIdx.x;
  const int lane = tid & 63;
  const int wv = tid >> 6;
  const int l15 = lane & 15;
  const int kg = lane >> 4;
  const int col = wgl * 16 + l15;
  const int bt0 = wv * 2;

  // ---- B into registers, fragment layout (loop-invariant) ----
  bf16x8 breg[NK][4];
  #pragma unroll
  for (int kk = 0; kk < NK; ++kk)
    #pragma unroll
    for (int g = 0; g < 4; ++g)
      breg[kk][g] = *reinterpret_cast<const bf16x8*>(
          whh + (size_t)(g * H + wgl * 16 + l15) * H + kk * 32 + kg * 8);

  float bgate[4];
  #pragma unroll
  for (int g = 0; g < 4; ++g) bgate[g] = bias[g * H + col];

  float cst[2][4];
  #pragma unroll
  for (int i = 0; i < 2; ++i)
    #pragma unroll
    for (int r = 0; r < 4; ++r) cst[i][r] = 0.f;

  for (int t = 0; t < 32; ++t) {
    int tin = REV ? (31 - t) : t;

    // acc initialized from input projection + bias (hides under the poll;
    // MFMA accumulates on top -- same arithmetic as epilogue-add).
    f32x4 acc[2][4];
    #pragma unroll
    for (int bt = 0; bt < 2; ++bt)
      #pragma unroll
      for (int r = 0; r < 4; ++r) {
        int b = (bt0 + bt) * 16 + kg * 4 + r;
        int ii = idx[tin * BATCH + b];
        #pragma unroll
        for (int g = 0; g < 4; ++g)
          acc[bt][g][r] = wih[(size_t)(g * H + col) * DIN + ii] + bgate[g];
      }

    if (t > 0) {
      // Poll producer flags through the XCD-local L2.
      const unsigned want = (unsigned)t;
      for (;;) {
        unsigned v = load_l2_dword(flags + (lane & (NWG - 1)));
        if (__all(v >= want)) break;
        __builtin_amdgcn_s_sleep(1);
      }
      __builtin_amdgcn_sched_barrier(0);

      // Burst-issue all A-fragment loads (L2-local, FIFO), consume halves.
      const __hip_bfloat16* hprev = hist + (size_t)(t - 1) * (BATCH * H);
      i32x4 a[2][NK];
      #pragma unroll
      for (int kk = 0; kk < NK; ++kk) {
        int kb = kk * 32 + kg * 8;
        a[0][kk] = load_l2_16(hprev + (size_t)(bt0 * 16 + l15) * H + kb);
        a[1][kk] = load_l2_16(hprev + (size_t)((bt0 + 1) * 16 + l15) * H + kb);
      }
      if constexpr (NK == 16) { asm volatile("s_waitcnt vmcnt(16)" ::: "memory"); }
      else                    { asm volatile("s_waitcnt vmcnt(8)" ::: "memory"); }
      __builtin_amdgcn_sched_barrier(0);
      #pragma unroll
      for (int kk = 0; kk < NK / 2; ++kk) {
        bf16x8 a0 = __builtin_bit_cast(bf16x8, a[0][kk]);
        bf16x8 a1 = __builtin_bit_cast(bf16x8, a[1][kk]);
        #pragma unroll
        for (int g = 0; g < 4; ++g) {
          acc[0][g] = __builtin_amdgcn_mfma_f32_16x16x32_bf16(a0, breg[kk][g], acc[0][g], 0, 0, 0);
          acc[1][g] = __builtin_amdgcn_mfma_f32_16x16x32_bf16(a1, breg[kk][g], acc[1][g], 0, 0, 0);
        }
      }
      asm volatile("s_waitcnt vmcnt(0)" ::: "memory");
      __builtin_amdgcn_sched_barrier(0);
      #pragma unroll
      for (int kk = NK / 2; kk < NK; ++kk) {
        bf16x8 a0 = __builtin_bit_cast(bf16x8, a[0][kk]);
        bf16x8 a1 = __builtin_bit_cast(bf16x8, a[1][kk]);
        #pragma unroll
        for (int g = 0; g < 4; ++g) {
          acc[0][g] = __builtin_amdgcn_mfma_f32_16x16x32_bf16(a0, breg[kk][g], acc[0][g], 0, 0, 0);
          acc[1][g] = __builtin_amdgcn_mfma_f32_16x16x32_bf16(a1, breg[kk][g], acc[1][g], 0, 0, 0);
        }
      }
    }

    // Cell update; h -> LDS bounce -> one coalesced 16B sc0 store/thread.
    #pragma unroll
    for (int bt = 0; bt < 2; ++bt) {
      #pragma unroll
      for (int r = 0; r < 4; ++r) {
        int b = (bt0 + bt) * 16 + kg * 4 + r;
        float gi = acc[bt][0][r];
        float gf = acc[bt][1][r];
        float gg = acc[bt][2][r];
        float go = acc[bt][3][r];
        float c = sigf(gf) * cst[bt][r] + sigf(gi) * tanhfast(gg);
        cst[bt][r] = c;
        lds_h[b][l15] = __float2bfloat16(sigf(go) * tanhfast(c));
      }
    }
    __syncthreads();
    {
      int b = tid >> 1, o = (tid & 1) * 8;
      i32x4 v = *reinterpret_cast<const i32x4*>(&lds_h[b][o]);
      __hip_bfloat16* dst = hist + (size_t)t * (BATCH * H) + (size_t)b * H + wgl * 16 + o;
      store_l2_16(dst, v);
    }
    asm volatile("s_waitcnt vmcnt(0)" ::: "memory");
    __syncthreads();   // all waves' h stores are in L2
    if (tid == 0)
      store_l2_dword(flags + wgl, (unsigned)(t + 1));
  }
}

__global__ __launch_bounds__(256, 1) void lstm_kernel(
    const float* __restrict__ Wih_pf, const float* __restrict__ b_pf,
    const float* __restrict__ Wih_pb, const float* __restrict__ b_pb,
    const float* __restrict__ Wih_m,  const float* __restrict__ b_m,
    const int* __restrict__ src_idx,  const int* __restrict__ tgt_idx,
    const __hip_bfloat16* __restrict__ whh_pf_b, const __hip_bfloat16* __restrict__ whh_pb_b,
    const __hip_bfloat16* __restrict__ whh_m_b,
    __hip_bfloat16* __restrict__ hf, __hip_bfloat16* __restrict__ hb,
    __hip_bfloat16* __restrict__ hm,
    unsigned* __restrict__ ctl)
{
  __shared__ __align__(16) __hip_bfloat16 lds_h[128][24];

  // ---- registration: which XCD am I on, what's my rank there ----
  unsigned xcc;
  asm volatile("s_getreg_b32 %0, hwreg(HW_REG_XCC_ID)" : "=s"(xcc));
  xcc &= 7;
  unsigned* srank = reinterpret_cast<unsigned*>(lds_h);
  if (threadIdx.x == 0) {
    unsigned r = __hip_atomic_fetch_add(&ctl[xcc], 1u, __ATOMIC_RELAXED, __HIP_MEMORY_SCOPE_AGENT);
    asm volatile("s_waitcnt vmcnt(0)" ::: "memory");   // cnt-add visible before total-add
    __hip_atomic_fetch_add(&ctl[8], 1u, __ATOMIC_RELAXED, __HIP_MEMORY_SCOPE_AGENT);
    while (__hip_atomic_load(&ctl[8], __ATOMIC_RELAXED, __HIP_MEMORY_SCOPE_AGENT) < (unsigned)NWGS)
      __builtin_amdgcn_s_sleep(8);
    srank[0] = r;
  }
  __syncthreads();
  unsigned rank = srank[0];
  __syncthreads();   // everyone read srank before LDS reuse

  unsigned counts[8];
  #pragma unroll
  for (int x = 0; x < 8; ++x)
    counts[x] = __hip_atomic_load(&ctl[x], __ATOMIC_RELAXED, __HIP_MEMORY_SCOPE_AGENT);

  // Greedy deterministic assignment (identical in every WG): modern(32) on
  // the fullest XCD, then pf(16), pb(16). Pigeonhole with 256 WGs / 8 XCDs
  // guarantees feasibility; multiple groups may share an XCD.
  int role = -1, wgl = 0;
  {
    unsigned rem[8];
    #pragma unroll
    for (int x = 0; x < 8; ++x) rem[x] = counts[x];
    const unsigned needs[3] = {32u, 16u, 16u};
    for (int g = 0; g < 3; ++g) {
      int best = 0;
      for (int x = 1; x < 8; ++x) if (rem[x] > rem[best]) best = x;
      unsigned base = counts[best] - rem[best];
      if ((int)xcc == best && rank >= base && rank < base + needs[g]) {
        role = g; wgl = (int)(rank - base);
      }
      rem[best] -= (rem[best] >= needs[g]) ? needs[g] : rem[best];
    }
  }
  if (role < 0) return;

  if (role == 0)
    lstm_body<HMOD, 32, false>(Wih_m, b_m, tgt_idx, whh_m_b, hm, ctl + 32, wgl, lds_h);
  else if (role == 1)
    lstm_body<HP, 16, false>(Wih_pf, b_pf, src_idx, whh_pf_b, hf, ctl + 64, wgl, lds_h);
  else
    lstm_body<HP, 16, true>(Wih_pb, b_pb, src_idx, whh_pb_b, hb, ctl + 96, wgl, lds_h);
}

__global__ __launch_bounds__(256, 1) void proj_kernel(
    const __hip_bfloat16* __restrict__ hf, const __hip_bfloat16* __restrict__ hb,
    const __hip_bfloat16* __restrict__ hm,
    const __hip_bfloat16* __restrict__ wsub_b, const __hip_bfloat16* __restrict__ wins_b,
    const float* __restrict__ b_sub, const float* __restrict__ b_ins,
    float* __restrict__ SPs, float* __restrict__ SPi,
    float* __restrict__ SMs, float* __restrict__ SMi)
{
  int wg = blockIdx.x;
  bool prior = wg < 64;
  int rowbase = (wg & 63) * 64;
  const int lane = threadIdx.x & 63;
  const int wv = threadIdx.x >> 6;
  const int l15 = lane & 15;
  const int kg = lane >> 4;
  int arow = rowbase + wv * 16 + l15;

  f32x4 acc[2][4];
  #pragma unroll
  for (int i = 0; i < 2; ++i)
    #pragma unroll
    for (int ct = 0; ct < 4; ++ct) acc[i][ct] = (f32x4){0.f, 0.f, 0.f, 0.f};

  for (int kk = 0; kk < 16; ++kk) {
    int kb = kk * 32 + kg * 8;
    bf16x8 a;
    if (prior) {
      int p = arow >> 7, b = arow & 127;
      if (kb < HP) a = *reinterpret_cast<const bf16x8*>(hf + ((size_t)p * BATCH + b) * HP + kb);
      else         a = *reinterpret_cast<const bf16x8*>(hb + ((size_t)(31 - p) * BATCH + b) * HP + (kb - HP));
    } else {
      a = *reinterpret_cast<const bf16x8*>(hm + (size_t)arow * HMOD + kb);
    }
    #pragma unroll
    for (int ct = 0; ct < 4; ++ct) {
      bf16x8 bs = *reinterpret_cast<const bf16x8*>(wsub_b + (size_t)(ct * 16 + l15) * HMOD + kb);
      bf16x8 bi = *reinterpret_cast<const bf16x8*>(wins_b + (size_t)(ct * 16 + l15) * HMOD + kb);
      acc[0][ct] = __builtin_amdgcn_mfma_f32_16x16x32_bf16(a, bs, acc[0][ct], 0, 0, 0);
      acc[1][ct] = __builtin_amdgcn_mfma_f32_16x16x32_bf16(a, bi, acc[1][ct], 0, 0, 0);
    }
  }
  #pragma unroll
  for (int ct = 0; ct < 4; ++ct) {
    int colo = ct * 16 + l15;
    #pragma unroll
    for (int r = 0; r < 4; ++r) {
      int row = rowbase + wv * 16 + kg * 4 + r;
      if (prior) {
        SPs[(size_t)row * 64 + colo] = acc[0][ct][r] + (colo < OUTV ? b_sub[colo] : 0.f);
        SPi[(size_t)row * 64 + colo] = acc[1][ct][r] + (colo < OUTV ? b_ins[colo] : 0.f);
      } else {
        SMs[(size_t)row * 64 + colo] = acc[0][ct][r];
        SMi[(size_t)row * 64 + colo] = acc[1][ct][r];
      }
    }
  }
}

__global__ __launch_bounds__(256, 1) void out_kernel(
    const float* __restrict__ SPs, const float* __restrict__ SPi,
    const float* __restrict__ SMs, const float* __restrict__ SMi,
    const int* __restrict__ tgt_idx, float* __restrict__ out)
{
  int b = blockIdx.x;
  __shared__ float sps[32][66], spi[32][66], sms[32][66], smi[32][66];
  __shared__ int tg[32];
  for (int i = threadIdx.x; i < 32 * 64; i += 256) {
    int p = i >> 6, o = i & 63;
    size_t base = ((size_t)p * BATCH + b) * 64 + o;
    sps[p][o] = SPs[base]; spi[p][o] = SPi[base];
    sms[p][o] = SMs[base]; smi[p][o] = SMi[base];
  }
  if (threadIdx.x < 32) tg[threadIdx.x] = tgt_idx[threadIdx.x * BATCH + b];
  __syncthreads();

  for (int pr = threadIdx.x; pr < PLEN * MLEN; pr += 256) {
    int p = pr >> 5, m = pr & 31;
    float mxs = -1e30f, mxi = -1e30f;
    for (int o = 0; o < OUTV; ++o) {
      mxs = fmaxf(mxs, sps[p][o] + sms[m][o]);
      mxi = fmaxf(mxi, spi[p][o] + smi[m][o]);
    }
    float ss = 0.f, si = 0.f;
    for (int o = 0; o < OUTV; ++o) {
      ss += __expf(sps[p][o] + sms[m][o] - mxs);
      si += __expf(spi[p][o] + smi[m][o] - mxi);
    }
    float lses = mxs + __logf(ss);
    float lsei = mxi + __logf(si);
    size_t pm = (size_t)(p * MLEN + m) * BATCH + b;
    out[pm] = sps[p][52] + sms[m][52] - lses;
    out[OFF_END + pm] = spi[p][52] + smi[m][52] - lsei;
    if (m < 31) {
      int tt = tg[m + 1];
      size_t pms = (size_t)(p * 31 + m) * BATCH + b;
      out[OFF_SUB + pms] = sps[p][tt] + sms[m][tt] - lses;
      out[OFF_INS + pms] = spi[p][tt] + smi[m][tt] - lsei;
    }
  }
}

extern "C" void kernel_launch(void* const* d_in, const int* in_sizes, int n_in,
                              void* d_out, int out_size, void* d_ws, size_t ws_size,
                              hipStream_t stream) {
  const float* src_oh = (const float*)d_in[0];
  const float* Wih_pf = (const float*)d_in[2];
  const float* Whh_pf = (const float*)d_in[3];
  const float* b_pf   = (const float*)d_in[4];
  const float* Wih_pb = (const float*)d_in[5];
  const float* Whh_pb = (const float*)d_in[6];
  const float* b_pb   = (const float*)d_in[7];
  const float* Wih_m  = (const float*)d_in[8];
  const float* Whh_m  = (const float*)d_in[9];
  const float* b_m    = (const float*)d_in[10];
  const float* W_sub  = (const float*)d_in[11];
  const float* b_sub  = (const float*)d_in[12];
  const float* W_ins  = (const float*)d_in[13];
  const float* b_ins  = (const float*)d_in[14];
  const int*   tgt    = (const int*)d_in[15];

  char* ws = (char*)d_ws;
  unsigned* ctl = (unsigned*)(ws + WS_CNT);
  int* src_idx = (int*)(ws + WS_SRCIDX);
  __hip_bfloat16* whh_pf_b = (__hip_bfloat16*)(ws + WS_WHH_PF);
  __hip_bfloat16* whh_pb_b = (__hip_bfloat16*)(ws + WS_WHH_PB);
  __hip_bfloat16* whh_m_b  = (__hip_bfloat16*)(ws + WS_WHH_M);
  __hip_bfloat16* wsub_b   = (__hip_bfloat16*)(ws + WS_WSUB);
  __hip_bfloat16* wins_b   = (__hip_bfloat16*)(ws + WS_WINS);
  __hip_bfloat16* hf = (__hip_bfloat16*)(ws + WS_HF);
  __hip_bfloat16* hb = (__hip_bfloat16*)(ws + WS_HB);
  __hip_bfloat16* hm = (__hip_bfloat16*)(ws + WS_HM);
  float* SPs = (float*)(ws + WS_SPS);
  float* SPi = (float*)(ws + WS_SPI);
  float* SMs = (float*)(ws + WS_SMS);
  float* SMi = (float*)(ws + WS_SMI);

  hipMemsetAsync(ctl, 0, 1024, stream);
  prep_kernel<<<256, 256, 0, stream>>>(Whh_pf, Whh_pb, Whh_m, W_sub, W_ins, src_oh,
                                       whh_pf_b, whh_pb_b, whh_m_b, wsub_b, wins_b, src_idx);
  lstm_kernel<<<NWGS, 256, 0, stream>>>(Wih_pf, b_pf, Wih_pb, b_pb, Wih_m, b_m,
                                        src_idx, tgt, whh_pf_b, whh_pb_b, whh_m_b,
                                        hf, hb, hm, ctl);
  proj_kernel<<<128, 256, 0, stream>>>(hf, hb, hm, wsub_b, wins_b, b_sub, b_ins,
                                       SPs, SPi, SMs, SMi);
  out_kernel<<<128, 256, 0, stream>>>(SPs, SPi, SMs, SMi, tgt, (float*)d_out);
}

// Round 6
// 292.723 us; speedup vs baseline: 1.9217x; 1.2197x over previous
//
#include <hip/hip_runtime.h>
#include <hip/hip_bf16.h>

// EditModel: bidi prior LSTM (H=256) + modern LSTM (H=512) + factored
// logit heads. ctx@W^T = prior@W^T (+) modern@W^T so no [P,M,B,2H] tensor.
//
// LSTM phase is XCD-LOCAL (WGs self-organize via HW_REG_XCC_ID; h + flags
// through the XCD's L2 with sc0 ops). R6: fragment-tiled h layout (1KB
// contiguous A bursts) + LDS-B with vmcnt-counted quarter overlap, on the
// PROVEN sync protocol (sleep-poll, <=64KB LDS, scattered 2B h-stores).
// R5's sleepless ring poll (flag-line read-starvation livelock) and 72KB
// LDS are both reverted.

#define PLEN 32
#define MLEN 32
#define BATCH 128
#define HP 256
#define HMOD 512
#define DIN 54
#define OUTV 53
#define NWGS 256

typedef __bf16 bf16x8 __attribute__((ext_vector_type(8)));
typedef float f32x4 __attribute__((ext_vector_type(4)));
typedef int i32x4 __attribute__((ext_vector_type(4)));

// ---- workspace layout (bytes) ----
// ctl (u32): [0..7] per-XCD reg count, [8] total, [32..63] flags modern,
//            [64..79] flags pf, [96..111] flags pb   (memset 1024B each call)
#define WS_CNT      0
#define WS_SRCIDX   1024
#define WS_WHH_PF   17408
#define WS_WHH_PB   541696
#define WS_WHH_M    1065984
#define WS_WSUB     3163136
#define WS_WINS     3228672
#define WS_HF       3294208
#define WS_HB       5391360
#define WS_HM       7488512
#define WS_SPS      11682816
#define WS_SPI      12731392
#define WS_SMS      13779968
#define WS_SMI      14828544

#define OFF_END 131072
#define OFF_SUB 262144
#define OFF_INS 389120

__device__ __forceinline__ float sigf(float x) { return 1.0f / (1.0f + __expf(-x)); }
__device__ __forceinline__ float tanhfast(float x) {
  x = fminf(15.0f, fmaxf(-15.0f, x));
  float e = __expf(2.0f * x);
  return (e - 1.0f) / (e + 1.0f);
}

// Intra-XCD coherent ops: sc0 = bypass L1, meet at the XCD-shared L2.
__device__ __forceinline__ i32x4 load_l2_16(const void* p) {
  i32x4 r;
  asm volatile("global_load_dwordx4 %0, %1, off sc0" : "=v"(r) : "v"(p) : "memory");
  return r;
}
__device__ __forceinline__ void store_l2_short(void* p, unsigned v) {
  asm volatile("global_store_short %0, %1, off sc0" :: "v"(p), "v"(v) : "memory");
}
__device__ __forceinline__ void store_l2_dword(void* p, unsigned v) {
  asm volatile("global_store_dword %0, %1, off sc0" :: "v"(p), "v"(v) : "memory");
}
__device__ __forceinline__ unsigned load_l2_dword(const void* p) {
  unsigned v;
  asm volatile("global_load_dword %0, %1, off sc0\n\ts_waitcnt vmcnt(0)"
               : "=v"(v) : "v"(p) : "memory");
  return v;
}

#define VMWAIT(n) do { asm volatile("s_waitcnt vmcnt(" #n ")" ::: "memory"); \
                       __builtin_amdgcn_sched_barrier(0); } while (0)

__global__ void prep_kernel(const float* __restrict__ Whh_pf, const float* __restrict__ Whh_pb,
                            const float* __restrict__ Whh_m,
                            const float* __restrict__ W_sub, const float* __restrict__ W_ins,
                            const float* __restrict__ src_oh,
                            __hip_bfloat16* __restrict__ whh_pf_b, __hip_bfloat16* __restrict__ whh_pb_b,
                            __hip_bfloat16* __restrict__ whh_m_b,
                            __hip_bfloat16* __restrict__ wsub_b, __hip_bfloat16* __restrict__ wins_b,
                            int* __restrict__ src_idx)
{
  int tid = blockIdx.x * blockDim.x + threadIdx.x;
  int stride = gridDim.x * blockDim.x;
  for (int k = tid; k < 4 * HP * HP; k += stride) {
    whh_pf_b[k] = __float2bfloat16(Whh_pf[k]);
    whh_pb_b[k] = __float2bfloat16(Whh_pb[k]);
  }
  for (int k = tid; k < 4 * HMOD * HMOD; k += stride)
    whh_m_b[k] = __float2bfloat16(Whh_m[k]);
  for (int k = tid; k < 64 * HMOD; k += stride) {
    int r = k >> 9, c = k & 511;
    wsub_b[k] = __float2bfloat16(r < OUTV ? W_sub[r * HMOD + c] : 0.0f);
    wins_b[k] = __float2bfloat16(r < OUTV ? W_ins[r * HMOD + c] : 0.0f);
  }
  for (int k = tid; k < PLEN * BATCH; k += stride) {
    const float* row = src_oh + (size_t)k * DIN;
    int idx = 0;
    for (int j = 0; j < DIN; ++j) if (row[j] > 0.5f) idx = j;
    src_idx[k] = idx;
  }
}

// h history layout, per LSTM (NK = H/32 k-blocks):
//   tile(t, btile, kk) = 512 bf16 (1KB) at ((t*8 + btile)*NK + kk)*512
//   elem within tile: (m*4 + kgc)*8 + j, where m = b&15, k = kk*32 + kgc*8 + j.
// A wave's MFMA A-fragment load (lane kg*16+l15 takes m=l15, slot kg) covers
// one full tile contiguously -> one 1KB burst per wave-load.

#define DO_QUARTER(Q0)                                                          \
  _Pragma("unroll")                                                             \
  for (int kk2 = 0; kk2 < NK / 4; ++kk2) {                                      \
    bf16x8 a0 = __builtin_bit_cast(bf16x8, a[0][(Q0) + kk2]);                   \
    bf16x8 a1 = __builtin_bit_cast(bf16x8, a[1][(Q0) + kk2]);                   \
    _Pragma("unroll")                                                           \
    for (int g = 0; g < 4; ++g) {                                               \
      bf16x8 bfr = *reinterpret_cast<const bf16x8*>(                            \
          ldsB + ((((Q0) + kk2) * 4 + g) * 64 + lane) * 16);                    \
      acc[0][g] = __builtin_amdgcn_mfma_f32_16x16x32_bf16(a0, bfr, acc[0][g], 0, 0, 0); \
      acc[1][g] = __builtin_amdgcn_mfma_f32_16x16x32_bf16(a1, bfr, acc[1][g], 0, 0, 0); \
    }                                                                           \
  }

template<int H, int NWG, bool REV>
__device__ __forceinline__ void lstm_body(
    const float* __restrict__ wih, const float* __restrict__ bias,
    const int* __restrict__ idx, const __hip_bfloat16* __restrict__ whh,
    __hip_bfloat16* __restrict__ hist, unsigned* flags, int wgl, char* ldsB)
{
  constexpr int NK = H / 32;
  constexpr int CPR = H / 8;       // 16B chunks per weight row
  const int tid = threadIdx.x;
  const int lane = tid & 63;
  const int wv = tid >> 6;
  const int l15 = lane & 15;
  const int kg = lane >> 4;
  const int col = wgl * 16 + l15;
  const int bt0 = wv * 2;
  const int aoff = l15 * 32 + kg * 8;     // A-fragment offset within a 1KB tile
  const int kgc  = (wgl & 1) * 2 + (l15 >> 3);  // this col's kg-slot in its tile
  const int jj   = l15 & 7;
  const int kkw  = wgl >> 1;              // this WG's k-block

  // ---- stage Whh slice into LDS, fragment order (once) ----
  for (int ch = tid; ch < 64 * CPR; ch += 256) {
    int r = ch / CPR, cb = ch % CPR;      // r = g*16+c, cb = kk*4+kg2
    int g = r >> 4, c = r & 15;
    int kk = cb >> 2, kg2 = cb & 3;
    i32x4 v = *reinterpret_cast<const i32x4*>(
        reinterpret_cast<const char*>(whh) + ((size_t)(g * H + wgl * 16 + c) * H) * 2 + cb * 16);
    *reinterpret_cast<i32x4*>(ldsB + (((kk * 4 + g) * 64) + kg2 * 16 + c) * 16) = v;
  }

  float bgate[4];
  #pragma unroll
  for (int g = 0; g < 4; ++g) bgate[g] = bias[g * H + col];

  float cst[2][4];
  #pragma unroll
  for (int i = 0; i < 2; ++i)
    #pragma unroll
    for (int r = 0; r < 4; ++r) cst[i][r] = 0.f;

  __syncthreads();   // LDS B ready

  for (int t = 0; t < 32; ++t) {
    int tin = REV ? (31 - t) : t;

    // Input-projection gathers (normal cached loads). Issued before the
    // poll / A burst, so they are always OLDER than the A loads -- the
    // counted vmcnt quarters below therefore retire them first (safe).
    float win[2][4][4];
    #pragma unroll
    for (int bt = 0; bt < 2; ++bt)
      #pragma unroll
      for (int r = 0; r < 4; ++r) {
        int b = (bt0 + bt) * 16 + kg * 4 + r;
        int ii = idx[tin * BATCH + b];
        #pragma unroll
        for (int g = 0; g < 4; ++g)
          win[bt][r][g] = wih[(size_t)(g * H + col) * DIN + ii] + bgate[g];
      }

    f32x4 acc[2][4];
    #pragma unroll
    for (int i = 0; i < 2; ++i)
      #pragma unroll
      for (int g = 0; g < 4; ++g) acc[i][g] = (f32x4){0.f, 0.f, 0.f, 0.f};

    if (t > 0) {
      // Wave-0-only sleep-poll (proven protocol); other waves park at the
      // barrier -> 4x less flag-line traffic, no read-starvation livelock.
      if (wv == 0) {
        const unsigned want = (unsigned)t;
        for (;;) {
          unsigned v = load_l2_dword(flags + (lane & (NWG - 1)));
          if (__all(v >= want)) break;
          __builtin_amdgcn_s_sleep(1);
        }
      }
      __syncthreads();
      __builtin_amdgcn_sched_barrier(0);

      // Burst-issue all A-fragment tile loads (contiguous 1KB per wave-load),
      // consume in quarters with counted vmcnt so LDS B-reads + MFMA overlap
      // the remaining load returns.
      const __hip_bfloat16* hp = hist;
      const size_t tb = (size_t)(t - 1) * 8;
      i32x4 a[2][NK];
      #pragma unroll
      for (int kk = 0; kk < NK; ++kk) {
        a[0][kk] = load_l2_16(hp + ((tb + bt0) * NK + kk) * 512 + aoff);
        a[1][kk] = load_l2_16(hp + ((tb + bt0 + 1) * NK + kk) * 512 + aoff);
      }
      if constexpr (NK == 16) {
        VMWAIT(24); DO_QUARTER(0);
        VMWAIT(16); DO_QUARTER(4);
        VMWAIT(8);  DO_QUARTER(8);
        VMWAIT(0);  DO_QUARTER(12);
      } else {
        VMWAIT(12); DO_QUARTER(0);
        VMWAIT(8);  DO_QUARTER(2);
        VMWAIT(4);  DO_QUARTER(4);
        VMWAIT(0);  DO_QUARTER(6);
      }
    }

    // Cell update; h -> scattered 2B sc0 stores into the fragment-tiled
    // history (16 lanes of a group cover 32B contiguous -> coalescable).
    #pragma unroll
    for (int bt = 0; bt < 2; ++bt) {
      #pragma unroll
      for (int r = 0; r < 4; ++r) {
        int b = (bt0 + bt) * 16 + kg * 4 + r;
        float gi = acc[bt][0][r] + win[bt][r][0];
        float gf = acc[bt][1][r] + win[bt][r][1];
        float gg = acc[bt][2][r] + win[bt][r][2];
        float go = acc[bt][3][r] + win[bt][r][3];
        float c = sigf(gf) * cst[bt][r] + sigf(gi) * tanhfast(gg);
        cst[bt][r] = c;
        __hip_bfloat16 hv = __float2bfloat16(sigf(go) * tanhfast(c));
        unsigned hbits = (unsigned)__builtin_bit_cast(unsigned short, hv);
        int btile = bt0 + bt;
        int m = kg * 4 + r;
        __hip_bfloat16* dst = hist + ((size_t)(t * 8 + btile) * NK + kkw) * 512
                              + (m * 4 + kgc) * 8 + jj;
        store_l2_short(dst, hbits);
      }
    }
    asm volatile("s_waitcnt vmcnt(0)" ::: "memory");
    __syncthreads();   // all waves' h stores are in L2
    if (tid == 0)
      store_l2_dword(flags + wgl, (unsigned)(t + 1));
  }
}

__global__ __launch_bounds__(256, 1) void lstm_kernel(
    const float* __restrict__ Wih_pf, const float* __restrict__ b_pf,
    const float* __restrict__ Wih_pb, const float* __restrict__ b_pb,
    const float* __restrict__ Wih_m,  const float* __restrict__ b_m,
    const int* __restrict__ src_idx,  const int* __restrict__ tgt_idx,
    const __hip_bfloat16* __restrict__ whh_pf_b, const __hip_bfloat16* __restrict__ whh_pb_b,
    const __hip_bfloat16* __restrict__ whh_m_b,
    __hip_bfloat16* __restrict__ hf, __hip_bfloat16* __restrict__ hb,
    __hip_bfloat16* __restrict__ hm,
    unsigned* __restrict__ ctl)
{
  __shared__ __align__(16) char ldsB[65536];   // exactly 64KB total static LDS

  // ---- registration: which XCD am I on, what's my rank there ----
  unsigned xcc;
  asm volatile("s_getreg_b32 %0, hwreg(HW_REG_XCC_ID)" : "=s"(xcc));
  xcc &= 7;
  unsigned* srank = reinterpret_cast<unsigned*>(ldsB);
  if (threadIdx.x == 0) {
    unsigned r = __hip_atomic_fetch_add(&ctl[xcc], 1u, __ATOMIC_RELAXED, __HIP_MEMORY_SCOPE_AGENT);
    asm volatile("s_waitcnt vmcnt(0)" ::: "memory");   // cnt-add visible before total-add
    __hip_atomic_fetch_add(&ctl[8], 1u, __ATOMIC_RELAXED, __HIP_MEMORY_SCOPE_AGENT);
    while (__hip_atomic_load(&ctl[8], __ATOMIC_RELAXED, __HIP_MEMORY_SCOPE_AGENT) < (unsigned)NWGS)
      __builtin_amdgcn_s_sleep(8);
    srank[0] = r;
  }
  __syncthreads();
  unsigned rank = srank[0];
  __syncthreads();   // everyone read srank before ldsB is reused for B

  unsigned counts[8];
  #pragma unroll
  for (int x = 0; x < 8; ++x)
    counts[x] = __hip_atomic_load(&ctl[x], __ATOMIC_RELAXED, __HIP_MEMORY_SCOPE_AGENT);

  // Greedy deterministic assignment (identical in every WG): modern(32) on
  // the fullest XCD, then pf(16), pb(16). Pigeonhole with 256 WGs / 8 XCDs
  // guarantees feasibility; multiple groups may share an XCD.
  int role = -1, wgl = 0;
  {
    unsigned rem[8];
    #pragma unroll
    for (int x = 0; x < 8; ++x) rem[x] = counts[x];
    const unsigned needs[3] = {32u, 16u, 16u};
    for (int g = 0; g < 3; ++g) {
      int best = 0;
      for (int x = 1; x < 8; ++x) if (rem[x] > rem[best]) best = x;
      unsigned base = counts[best] - rem[best];
      if ((int)xcc == best && rank >= base && rank < base + needs[g]) {
        role = g; wgl = (int)(rank - base);
      }
      rem[best] -= (rem[best] >= needs[g]) ? needs[g] : rem[best];
    }
  }
  if (role < 0) return;

  if (role == 0)
    lstm_body<HMOD, 32, false>(Wih_m, b_m, tgt_idx, whh_m_b, hm, ctl + 32, wgl, ldsB);
  else if (role == 1)
    lstm_body<HP, 16, false>(Wih_pf, b_pf, src_idx, whh_pf_b, hf, ctl + 64, wgl, ldsB);
  else
    lstm_body<HP, 16, true>(Wih_pb, b_pb, src_idx, whh_pb_b, hb, ctl + 96, wgl, ldsB);
}

__global__ __launch_bounds__(256, 1) void proj_kernel(
    const __hip_bfloat16* __restrict__ hf, const __hip_bfloat16* __restrict__ hb,
    const __hip_bfloat16* __restrict__ hm,
    const __hip_bfloat16* __restrict__ wsub_b, const __hip_bfloat16* __restrict__ wins_b,
    const float* __restrict__ b_sub, const float* __restrict__ b_ins,
    float* __restrict__ SPs, float* __restrict__ SPi,
    float* __restrict__ SMs, float* __restrict__ SMi)
{
  int wg = blockIdx.x;
  bool prior = wg < 64;
  int rowbase = (wg & 63) * 64;
  const int lane = threadIdx.x & 63;
  const int wv = threadIdx.x >> 6;
  const int l15 = lane & 15;
  const int kg = lane >> 4;
  const int frag = l15 * 32 + kg * 8;
  int arow = rowbase + wv * 16 + l15;
  int tt = arow >> 7;                       // p (prior) or m (modern)
  int bt = ((arow & 127) >> 4);

  f32x4 acc[2][4];
  #pragma unroll
  for (int i = 0; i < 2; ++i)
    #pragma unroll
    for (int ct = 0; ct < 4; ++ct) acc[i][ct] = (f32x4){0.f, 0.f, 0.f, 0.f};

  for (int kk = 0; kk < 16; ++kk) {
    int kb = kk * 32 + kg * 8;
    bf16x8 a;
    if (prior) {
      if (kk < 8) a = *reinterpret_cast<const bf16x8*>(hf + ((size_t)(tt * 8 + bt) * 8 + kk) * 512 + frag);
      else        a = *reinterpret_cast<const bf16x8*>(hb + ((size_t)((31 - tt) * 8 + bt) * 8 + (kk - 8)) * 512 + frag);
    } else {
      a = *reinterpret_cast<const bf16x8*>(hm + ((size_t)(tt * 8 + bt) * 16 + kk) * 512 + frag);
    }
    #pragma unroll
    for (int ct = 0; ct < 4; ++ct) {
      bf16x8 bs = *reinterpret_cast<const bf16x8*>(wsub_b + (size_t)(ct * 16 + l15) * HMOD + kb);
      bf16x8 bi = *reinterpret_cast<const bf16x8*>(wins_b + (size_t)(ct * 16 + l15) * HMOD + kb);
      acc[0][ct] = __builtin_amdgcn_mfma_f32_16x16x32_bf16(a, bs, acc[0][ct], 0, 0, 0);
      acc[1][ct] = __builtin_amdgcn_mfma_f32_16x16x32_bf16(a, bi, acc[1][ct], 0, 0, 0);
    }
  }
  #pragma unroll
  for (int ct = 0; ct < 4; ++ct) {
    int colo = ct * 16 + l15;
    #pragma unroll
    for (int r = 0; r < 4; ++r) {
      int row = rowbase + wv * 16 + kg * 4 + r;
      if (prior) {
        SPs[(size_t)row * 64 + colo] = acc[0][ct][r] + (colo < OUTV ? b_sub[colo] : 0.f);
        SPi[(size_t)row * 64 + colo] = acc[1][ct][r] + (colo < OUTV ? b_ins[colo] : 0.f);
      } else {
        SMs[(size_t)row * 64 + colo] = acc[0][ct][r];
        SMi[(size_t)row * 64 + colo] = acc[1][ct][r];
      }
    }
  }
}

__global__ __launch_bounds__(256, 1) void out_kernel(
    const float* __restrict__ SPs, const float* __restrict__ SPi,
    const float* __restrict__ SMs, const float* __restrict__ SMi,
    const int* __restrict__ tgt_idx, float* __restrict__ out)
{
  int b = blockIdx.x;
  __shared__ float sps[32][66], spi[32][66], sms[32][66], smi[32][66];
  __shared__ int tg[32];
  for (int i = threadIdx.x; i < 32 * 64; i += 256) {
    int p = i >> 6, o = i & 63;
    size_t base = ((size_t)p * BATCH + b) * 64 + o;
    sps[p][o] = SPs[base]; spi[p][o] = SPi[base];
    sms[p][o] = SMs[base]; smi[p][o] = SMi[base];
  }
  if (threadIdx.x < 32) tg[threadIdx.x] = tgt_idx[threadIdx.x * BATCH + b];
  __syncthreads();

  for (int pr = threadIdx.x; pr < PLEN * MLEN; pr += 256) {
    int p = pr >> 5, m = pr & 31;
    float mxs = -1e30f, mxi = -1e30f;
    for (int o = 0; o < OUTV; ++o) {
      mxs = fmaxf(mxs, sps[p][o] + sms[m][o]);
      mxi = fmaxf(mxi, spi[p][o] + smi[m][o]);
    }
    float ss = 0.f, si = 0.f;
    for (int o = 0; o < OUTV; ++o) {
      ss += __expf(sps[p][o] + sms[m][o] - mxs);
      si += __expf(spi[p][o] + smi[m][o] - mxi);
    }
    float lses = mxs + __logf(ss);
    float lsei = mxi + __logf(si);
    size_t pm = (size_t)(p * MLEN + m) * BATCH + b;
    out[pm] = sps[p][52] + sms[m][52] - lses;
    out[OFF_END + pm] = spi[p][52] + smi[m][52] - lsei;
    if (m < 31) {
      int ttg = tg[m + 1];
      size_t pms = (size_t)(p * 31 + m) * BATCH + b;
      out[OFF_SUB + pms] = sps[p][ttg] + sms[m][ttg] - lses;
      out[OFF_INS + pms] = spi[p][ttg] + smi[m][ttg] - lsei;
    }
  }
}

extern "C" void kernel_launch(void* const* d_in, const int* in_sizes, int n_in,
                              void* d_out, int out_size, void* d_ws, size_t ws_size,
                              hipStream_t stream) {
  const float* src_oh = (const float*)d_in[0];
  const float* Wih_pf = (const float*)d_in[2];
  const float* Whh_pf = (const float*)d_in[3];
  const float* b_pf   = (const float*)d_in[4];
  const float* Wih_pb = (const float*)d_in[5];
  const float* Whh_pb = (const float*)d_in[6];
  const float* b_pb   = (const float*)d_in[7];
  const float* Wih_m  = (const float*)d_in[8];
  const float* Whh_m  = (const float*)d_in[9];
  const float* b_m    = (const float*)d_in[10];
  const float* W_sub  = (const float*)d_in[11];
  const float* b_sub  = (const float*)d_in[12];
  const float* W_ins  = (const float*)d_in[13];
  const float* b_ins  = (const float*)d_in[14];
  const int*   tgt    = (const int*)d_in[15];

  char* ws = (char*)d_ws;
  unsigned* ctl = (unsigned*)(ws + WS_CNT);
  int* src_idx = (int*)(ws + WS_SRCIDX);
  __hip_bfloat16* whh_pf_b = (__hip_bfloat16*)(ws + WS_WHH_PF);
  __hip_bfloat16* whh_pb_b = (__hip_bfloat16*)(ws + WS_WHH_PB);
  __hip_bfloat16* whh_m_b  = (__hip_bfloat16*)(ws + WS_WHH_M);
  __hip_bfloat16* wsub_b   = (__hip_bfloat16*)(ws + WS_WSUB);
  __hip_bfloat16* wins_b   = (__hip_bfloat16*)(ws + WS_WINS);
  __hip_bfloat16* hf = (__hip_bfloat16*)(ws + WS_HF);
  __hip_bfloat16* hb = (__hip_bfloat16*)(ws + WS_HB);
  __hip_bfloat16* hm = (__hip_bfloat16*)(ws + WS_HM);
  float* SPs = (float*)(ws + WS_SPS);
  float* SPi = (float*)(ws + WS_SPI);
  float* SMs = (float*)(ws + WS_SMS);
  float* SMi = (float*)(ws + WS_SMI);

  hipMemsetAsync(ctl, 0, 1024, stream);
  prep_kernel<<<256, 256, 0, stream>>>(Whh_pf, Whh_pb, Whh_m, W_sub, W_ins, src_oh,
                                       whh_pf_b, whh_pb_b, whh_m_b, wsub_b, wins_b, src_idx);
  lstm_kernel<<<NWGS, 256, 0, stream>>>(Wih_pf, b_pf, Wih_pb, b_pb, Wih_m, b_m,
                                        src_idx, tgt, whh_pf_b, whh_pb_b, whh_m_b,
                                        hf, hb, hm, ctl);
  proj_kernel<<<128, 256, 0, stream>>>(hf, hb, hm, wsub_b, wins_b, b_sub, b_ins,
                                       SPs, SPi, SMs, SMi);
  out_kernel<<<128, 256, 0, stream>>>(SPs, SPi, SMs, SMi, tgt, (float*)d_out);
}